// Round 7
// baseline (238.568 us; speedup 1.0000x reference)
//
#include <hip/hip_runtime.h>
#include <math.h>

typedef unsigned short u16;
typedef unsigned int u32;
typedef __attribute__((ext_vector_type(8))) short short8;      // 8 bf16 (4 VGPRs) MFMA A/B frag
typedef __attribute__((ext_vector_type(8))) _Float16 half8;    // 8 f16 MFMA A/B frag
typedef __attribute__((ext_vector_type(4))) float f32x4;       // MFMA C/D frag

#define EPS 1e-8f

// ---------- helpers ----------
__device__ inline float bf2f(u16 u) {
    union { u32 i; float f; } v; v.i = ((u32)u) << 16; return v.f;
}
__device__ inline u16 f2bf(float f) {  // RNE
    union { float f; u32 u; } v; v.f = f;
    u32 r = v.u + 0x7fffu + ((v.u >> 16) & 1u);
    return (u16)(r >> 16);
}
__device__ inline u16 f2h(float f) {   // f32 -> f16 RNE
    _Float16 h = (_Float16)f;
    union { _Float16 hh; u16 u; } v; v.hh = h; return v.u;
}
__device__ inline u32 pack2(float a, float b) {
    return (u32)f2bf(a) | ((u32)f2bf(b) << 16);
}
__device__ inline float wave_sum(float v) {
    for (int off = 32; off; off >>= 1) v += __shfl_xor(v, off, 64);
    return v;
}

// ---- single-phase 64x64 tile, K=512: stage whole 64x512 into LDS (stride 520) ----
__device__ __forceinline__ void stage64x512(const u16* __restrict__ Ag, size_t lda,
                                            u16* __restrict__ As) {
    const int t = threadIdx.x;
    const int srow = t >> 2;
    const int c0 = (t & 3) * 8;
    #pragma unroll
    for (int kk = 0; kk < 16; kk++) {
        int c = c0 + kk * 32;
        *(uint4*)&As[srow * 520 + c] = *(const uint4*)&Ag[(size_t)srow * lda + c];
    }
}
__device__ __forceinline__ void mfma_k512(const u16* __restrict__ As,
                                          const u16* __restrict__ Bs,
                                          f32x4 (&acc)[2][2]) {
    const int t = threadIdx.x, lane = t & 63, w = t >> 6;
    const int wm = (w >> 1) * 32, wn = (w & 1) * 32;
    const int l16 = lane & 15, quad = lane >> 4;
    #pragma unroll
    for (int ks = 0; ks < 16; ks++) {
        short8 af[2], bfr[2];
        #pragma unroll
        for (int i = 0; i < 2; i++)
            af[i] = *(const short8*)&As[(wm + i * 16 + l16) * 520 + ks * 32 + quad * 8];
        #pragma unroll
        for (int j = 0; j < 2; j++)
            bfr[j] = *(const short8*)&Bs[(wn + j * 16 + l16) * 520 + ks * 32 + quad * 8];
        #pragma unroll
        for (int i = 0; i < 2; i++)
            #pragma unroll
            for (int j = 0; j < 2; j++)
                acc[i][j] = __builtin_amdgcn_mfma_f32_16x16x32_bf16(af[i], bfr[j], acc[i][j], 0, 0, 0);
    }
}

// ---------- K1: prep (now includes self-contained qqk) ----------
// [0,64):    qqk: q-proj + qk-proj from raw fp32 inputs -> qkb bf16
// [64,192):  vis rows: fp32-norm + bf16-norm (+ zero loss/corrSS in bid 64)
// [192,448): wv cvt -> bf16
// [448,704): wo cvt -> bf16
// [704,832): tm rows -> normalized bf16 negsb[512:]
// [832,896): wo -> transposed bf16 woT[c][j]
__global__ __launch_bounds__(256) void prep(const float* __restrict__ vis,
                                            const float* __restrict__ ipw,
                                            const float* __restrict__ opw,
                                            const float* __restrict__ tm,
                                            const float* __restrict__ ipb,
                                            float* __restrict__ vis_n,
                                            u16* __restrict__ vis_nb,
                                            u16* __restrict__ wvb,
                                            u16* __restrict__ wob,
                                            u16* __restrict__ negsb,
                                            u16* __restrict__ woT,
                                            u16* __restrict__ qkb,
                                            float* __restrict__ corrSS,
                                            float* __restrict__ loss0)
{
    __shared__ __align__(16) u16 SMEM[3 * 64 * 72];   // 27648 B (qqk: As|Bs|Qf; transposes: T)
    int bid = blockIdx.x;
    int t = threadIdx.x;
    if (bid >= 832) {                        // wo transpose -> bf16 woT[c][j]
        u16* T = SMEM;
        int idx = bid - 832;
        int a = idx >> 3, cb = idx & 7;
        int r = t >> 2, c0 = (t & 3) * 16;
        #pragma unroll
        for (int q = 0; q < 4; q++) {
            float4 v = *(const float4*)&opw[(size_t)(a * 64 + r) * 512 + cb * 64 + c0 + q * 4];
            T[(c0 + q * 4 + 0) * 72 + r] = f2bf(v.x);
            T[(c0 + q * 4 + 1) * 72 + r] = f2bf(v.y);
            T[(c0 + q * 4 + 2) * 72 + r] = f2bf(v.z);
            T[(c0 + q * 4 + 3) * 72 + r] = f2bf(v.w);
        }
        __syncthreads();
        int j = t >> 2, ch = (t & 3) * 16;
        *(uint4*)&woT[(size_t)(cb * 64 + j) * 512 + a * 64 + ch]     = *(const uint4*)&T[j * 72 + ch];
        *(uint4*)&woT[(size_t)(cb * 64 + j) * 512 + a * 64 + ch + 8] = *(const uint4*)&T[j * 72 + ch + 8];
        return;
    }
    if (bid >= 704) {                        // tm rows -> normalized negsb[512:]
        int wave = t >> 6, lane = t & 63;
        int j = 512 + (bid - 704) * 4 + wave;
        const float* row = tm + (size_t)(j - 512) * 512 + lane * 8;
        float4 x0 = *(const float4*)row;
        float4 x1 = *(const float4*)(row + 4);
        float ss = x0.x*x0.x + x0.y*x0.y + x0.z*x0.z + x0.w*x0.w
                 + x1.x*x1.x + x1.y*x1.y + x1.z*x1.z + x1.w*x1.w;
        ss = wave_sum(ss);
        float inv = 1.0f / fmaxf(sqrtf(ss), EPS);
        uint4 pk;
        pk.x = pack2(x0.x*inv, x0.y*inv); pk.y = pack2(x0.z*inv, x0.w*inv);
        pk.z = pack2(x1.x*inv, x1.y*inv); pk.w = pack2(x1.z*inv, x1.w*inv);
        *(uint4*)(negsb + (size_t)j * 512 + lane * 8) = pk;
        return;
    }
    if (bid >= 448) {                        // wo cvt
        int i = (bid - 448) * 1024 + t * 4;
        float4 v = *(const float4*)(opw + i);
        uint2 pk; pk.x = pack2(v.x, v.y); pk.y = pack2(v.z, v.w);
        *(uint2*)(wob + i) = pk;
        return;
    }
    if (bid >= 192) {                        // wv cvt
        int i = (bid - 192) * 1024 + t * 4;
        float4 v = *(const float4*)(ipw + 524288 + i);
        uint2 pk; pk.x = pack2(v.x, v.y); pk.y = pack2(v.z, v.w);
        *(uint2*)(wvb + i) = pk;
        return;
    }
    if (bid >= 64) {                         // vis rows
        if (bid == 64) {
            if (t == 0) loss0[0] = 0.0f;
            corrSS[t] = 0.0f;
            corrSS[t + 256] = 0.0f;
        }
        int wave = t >> 6, lane = t & 63;
        int b = (bid - 64) * 4 + wave;       // B = 512
        const float* row = vis + (size_t)b * 512 + lane * 8;
        float4 x0 = *(const float4*)row;
        float4 x1 = *(const float4*)(row + 4);
        float ss = x0.x*x0.x + x0.y*x0.y + x0.z*x0.z + x0.w*x0.w
                 + x1.x*x1.x + x1.y*x1.y + x1.z*x1.z + x1.w*x1.w;
        ss = wave_sum(ss);
        float inv = 1.0f / fmaxf(sqrtf(ss), EPS);
        float4 y0, y1;
        y0.x = x0.x*inv; y0.y = x0.y*inv; y0.z = x0.z*inv; y0.w = x0.w*inv;
        y1.x = x1.x*inv; y1.y = x1.y*inv; y1.z = x1.z*inv; y1.w = x1.w*inv;
        *(float4*)(vis_n + (size_t)b * 512 + lane * 8)     = y0;
        *(float4*)(vis_n + (size_t)b * 512 + lane * 8 + 4) = y1;
        uint4 pk;
        pk.x = pack2(y0.x, y0.y); pk.y = pack2(y0.z, y0.w);
        pk.z = pack2(y1.x, y1.y); pk.w = pack2(y1.z, y1.w);
        *(uint4*)(vis_nb + (size_t)b * 512 + lane * 8) = pk;
        return;
    }

    // ---- qqk: 64 blocks, self-contained from fp32 inputs ----
    u16* As = SMEM;              // 64x72 bf16
    u16* Bs = SMEM + 4608;       // 64x72
    u16* Qf = SMEM + 9216;       // 64x72 f16
    const int lane = t & 63, w = t >> 6;
    const int wm = (w >> 1) * 32, wn = (w & 1) * 32;
    const int l16 = lane & 15, quad = lane >> 4;
    const int srow = t >> 3, scol = (t & 7) * 8;
    const int m0 = (bid & 7) * 64, h = bid >> 3;
    const float* wkf = ipw + 262144;         // wk fp32 rows

    f32x4 acc[2][2];
    for (int i = 0; i < 2; i++)
        for (int j = 0; j < 2; j++)
            for (int e = 0; e < 4; e++) acc[i][j][e] = 0.f;

    for (int ko = 0; ko < 512; ko += 64) {
        __syncthreads();
        #pragma unroll
        for (int i = 0; i < 2; i++) {
            int row = i * 32 + srow;
            const float* ap = vis + (size_t)(m0 + row) * 512 + ko + scol;
            float4 a0 = *(const float4*)ap, a1 = *(const float4*)(ap + 4);
            uint4 pkA;
            pkA.x = pack2(a0.x, a0.y); pkA.y = pack2(a0.z, a0.w);
            pkA.z = pack2(a1.x, a1.y); pkA.w = pack2(a1.z, a1.w);
            *(uint4*)&As[row * 72 + scol] = pkA;
            const float* bp = ipw + (size_t)(h * 64 + row) * 512 + ko + scol;
            float4 b0 = *(const float4*)bp, b1 = *(const float4*)(bp + 4);
            uint4 pkB;
            pkB.x = pack2(b0.x, b0.y); pkB.y = pack2(b0.z, b0.w);
            pkB.z = pack2(b1.x, b1.y); pkB.w = pack2(b1.z, b1.w);
            *(uint4*)&Bs[row * 72 + scol] = pkB;
        }
        __syncthreads();
        #pragma unroll
        for (int ks = 0; ks < 2; ks++) {
            short8 af[2], bfr[2];
            #pragma unroll
            for (int i = 0; i < 2; i++)
                af[i] = *(const short8*)&As[(wm + i * 16 + l16) * 72 + ks * 32 + quad * 8];
            #pragma unroll
            for (int j = 0; j < 2; j++)
                bfr[j] = *(const short8*)&Bs[(wn + j * 16 + l16) * 72 + ks * 32 + quad * 8];
            #pragma unroll
            for (int i = 0; i < 2; i++)
                #pragma unroll
                for (int j = 0; j < 2; j++)
                    acc[i][j] = __builtin_amdgcn_mfma_f32_16x16x32_bf16(af[i], bfr[j], acc[i][j], 0, 0, 0);
        }
    }
    // epilogue: q (+bq) -> f16 in Qf
    #pragma unroll
    for (int i = 0; i < 2; i++)
        #pragma unroll
        for (int j = 0; j < 2; j++)
            #pragma unroll
            for (int r = 0; r < 4; r++) {
                int rl = wm + i * 16 + quad * 4 + r;
                int cl = wn + j * 16 + l16;
                Qf[rl * 72 + cl] = f2h(acc[i][j][r] + ipb[h * 64 + cl]);
            }
    // Phase B: per jt, inline transpose wk fp32 tile -> f16 Bs[j][d]
    for (int jt = 0; jt < 8; jt++) {
        __syncthreads();
        {
            int r = t >> 2, c0 = (t & 3) * 16;
            #pragma unroll
            for (int q = 0; q < 4; q++) {
                float4 v = *(const float4*)&wkf[(size_t)(h * 64 + r) * 512 + jt * 64 + c0 + q * 4];
                Bs[(c0 + q * 4 + 0) * 72 + r] = f2h(v.x);
                Bs[(c0 + q * 4 + 1) * 72 + r] = f2h(v.y);
                Bs[(c0 + q * 4 + 2) * 72 + r] = f2h(v.z);
                Bs[(c0 + q * 4 + 3) * 72 + r] = f2h(v.w);
            }
        }
        __syncthreads();
        f32x4 a2[2][2];
        for (int i = 0; i < 2; i++)
            for (int j = 0; j < 2; j++)
                for (int e = 0; e < 4; e++) a2[i][j][e] = 0.f;
        #pragma unroll
        for (int ks = 0; ks < 2; ks++) {
            half8 af[2], bfr[2];
            #pragma unroll
            for (int i = 0; i < 2; i++)
                af[i] = *(const half8*)&Qf[(wm + i * 16 + l16) * 72 + ks * 32 + quad * 8];
            #pragma unroll
            for (int j = 0; j < 2; j++)
                bfr[j] = *(const half8*)&Bs[(wn + j * 16 + l16) * 72 + ks * 32 + quad * 8];
            #pragma unroll
            for (int i = 0; i < 2; i++)
                #pragma unroll
                for (int j = 0; j < 2; j++)
                    a2[i][j] = __builtin_amdgcn_mfma_f32_16x16x32_f16(af[i], bfr[j], a2[i][j], 0, 0, 0);
        }
        #pragma unroll
        for (int i = 0; i < 2; i++)
            #pragma unroll
            for (int j = 0; j < 2; j++)
                #pragma unroll
                for (int r = 0; r < 4; r++) {
                    int rb = m0 + wm + i * 16 + quad * 4 + r;
                    int cj = jt * 64 + wn + j * 16 + l16;
                    qkb[((size_t)rb * 8 + h) * 512 + cj] = f2bf(a2[i][j][r]);
                }
    }
}

// ---------- K2: attention (fused tf stream, deep load prefetch); 512 x 1024 ----------
__global__ __launch_bounds__(1024) void attn(const float* __restrict__ tf,
                                             const float* __restrict__ vis_n,
                                             const u16* __restrict__ qkb,
                                             u16* __restrict__ u_allb,
                                             float* __restrict__ out_cs)
{
    __shared__ __align__(16) u16 Xs[96 * 520];
    __shared__ __align__(16) u16 Qs[16 * 520];
    __shared__ __align__(16) u16 Ps[16 * 104];
    __shared__ float Sc[16 * 100];
    __shared__ float sm_[96], srt[96], linv[8];

    const int b = blockIdx.x;
    const int t = threadIdx.x, w = t >> 6, lane = t & 63;
    const int l16 = lane & 15, quad = lane >> 4;

    if (w < 8) {
        *(uint4*)&Qs[w * 520 + lane * 8] = *(const uint4*)(qkb + ((size_t)b * 8 + w) * 512 + lane * 8);
    } else {
        uint4 z; z.x = 0; z.y = 0; z.z = 0; z.w = 0;
        *(uint4*)&Qs[w * 520 + lane * 8] = z;
    }
    const float4* v4 = (const float4*)(vis_n + (size_t)b * 512 + lane * 8);
    float4 va = v4[0], vbv = v4[1];

    // issue ALL 12 tf loads first (MLP), then consume
    float4 xr[6][2];
    #pragma unroll
    for (int i = 0; i < 6; i++) {
        const float4* pa = (const float4*)(tf + ((size_t)b * 96 + w + i * 16) * 512 + lane * 8);
        xr[i][0] = pa[0];
        xr[i][1] = pa[1];
    }
    float ssv[6], dtv[6];
    #pragma unroll
    for (int i = 0; i < 6; i++) {
        float4 a = xr[i][0], c = xr[i][1];
        ssv[i] = a.x*a.x + a.y*a.y + a.z*a.z + a.w*a.w
               + c.x*c.x + c.y*c.y + c.z*c.z + c.w*c.w;
        dtv[i] = a.x*va.x + a.y*va.y + a.z*va.z + a.w*va.w
               + c.x*vbv.x + c.y*vbv.y + c.z*vbv.z + c.w*vbv.w;
        uint4 pk;
        pk.x = pack2(a.x, a.y); pk.y = pack2(a.z, a.w);
        pk.z = pack2(c.x, c.y); pk.w = pack2(c.z, c.w);
        *(uint4*)&Xs[(w + i * 16) * 520 + lane * 8] = pk;
    }
    #pragma unroll
    for (int off = 32; off; off >>= 1) {
        #pragma unroll
        for (int i = 0; i < 6; i++) {
            ssv[i] += __shfl_xor(ssv[i], off, 64);
            dtv[i] += __shfl_xor(dtv[i], off, 64);
        }
    }
    if (lane == 0) {
        #pragma unroll
        for (int i = 0; i < 6; i++)
            sm_[w + i * 16] = dtv[i] / fmaxf(sqrtf(ssv[i]), EPS);
    }
    __syncthreads();

    if (w < 6) {
        f32x4 acc;
        for (int e = 0; e < 4; e++) acc[e] = 0.f;
        #pragma unroll
        for (int ks = 0; ks < 16; ks++) {
            short8 a = *(const short8*)&Xs[(w * 16 + l16) * 520 + ks * 32 + quad * 8];
            short8 q = *(const short8*)&Qs[l16 * 520 + ks * 32 + quad * 8];
            acc = __builtin_amdgcn_mfma_f32_16x16x32_bf16(a, q, acc, 0, 0, 0);
        }
        #pragma unroll
        for (int r = 0; r < 4; r++)
            Sc[l16 * 100 + w * 16 + quad * 4 + r] = acc[r] * 0.125f;
    }
    __syncthreads();

    if (w < 8) {
        float e0 = __expf(Sc[w * 100 + lane]);
        float e1 = (lane < 32) ? __expf(Sc[w * 100 + 64 + lane]) : 0.f;
        float l = wave_sum(e0 + e1);
        Ps[w * 104 + lane] = f2bf(e0);
        if (lane < 32) Ps[w * 104 + 64 + lane] = f2bf(e1);
        if (lane == 0) linv[w] = 1.0f / l;
    } else {
        Ps[w * 104 + lane] = 0;
        if (lane < 40) Ps[w * 104 + 64 + lane] = 0;
    }
    if (t < 96) {
        float v = sm_[t]; int r = 0;
        for (int j = 0; j < 96; j++) {
            float u = sm_[j];
            r += (u > v) || (u == v && j < t);
        }
        srt[r] = v;
    }
    __syncthreads();

    #pragma unroll
    for (int jj = 0; jj < 2; jj++) {
        int n0 = (w * 2 + jj) * 16;
        f32x4 acc;
        for (int e = 0; e < 4; e++) acc[e] = 0.f;
        #pragma unroll
        for (int ks = 0; ks < 3; ks++) {
            short8 ap = *(const short8*)&Ps[l16 * 104 + ks * 32 + quad * 8];
            short8 bx;
            #pragma unroll
            for (int j = 0; j < 8; j++)
                bx[j] = (short)Xs[(ks * 32 + quad * 8 + j) * 520 + n0 + l16];
            acc = __builtin_amdgcn_mfma_f32_16x16x32_bf16(ap, bx, acc, 0, 0, 0);
        }
        if (quad < 2) {
            #pragma unroll
            for (int r = 0; r < 4; r++) {
                int h = quad * 4 + r;
                u_allb[((size_t)b * 8 + h) * 512 + n0 + l16] = f2bf(acc[r] * linv[h]);
            }
        }
    }
    if (t < 3) {
        float mean = 0.f;
        #pragma unroll 8
        for (int i = 0; i < 32; i++) mean += srt[t * 32 + i];
        mean *= (1.0f / 32.0f);
        float var = 0.f;
        #pragma unroll 8
        for (int i = 0; i < 32; i++) { float d = srt[t * 32 + i] - mean; var += d * d; }
        var *= (1.0f / 31.0f);
        out_cs[b * 3 + t] = mean / (sqrtf(var) + 1e-6f);
    }
}

// ---------- K3: gmid (200 blocks, all independent, single-phase K=512) ----------
// [0,64):    ghead: ctx_h = u_h @ Wv_h^T + bv_h -> ctxb bf16
// [64,128):  ns_right: ns[:,512:1024] = vis_nb @ negsb[512:]^T
// [128,192): G = vis_nb @ woT^T (bf16)
// [192,200): vb[b] = vis_n[b] . bo
__global__ __launch_bounds__(256) void gmid(const u16* __restrict__ u_allb,
                                            const u16* __restrict__ wvb,
                                            const float* __restrict__ bv,
                                            u16* __restrict__ ctxb,
                                            const u16* __restrict__ vis_nb,
                                            const u16* __restrict__ negsb,
                                            float* __restrict__ ns,
                                            const u16* __restrict__ woT,
                                            u16* __restrict__ G,
                                            const float* __restrict__ opb,
                                            float* __restrict__ vb,
                                            const float* __restrict__ vis_n)
{
    __shared__ __align__(16) u16 As[64 * 520];
    __shared__ __align__(16) u16 Bs[64 * 520];
    const int bid = blockIdx.x;
    const int t = threadIdx.x, lane = t & 63, w = t >> 6;
    const int wm = (w >> 1) * 32, wn = (w & 1) * 32;
    const int l16 = lane & 15, quad = lane >> 4;

    if (bid >= 192) {
        // ---- vb: 8 blocks x 4 waves x 16 b ----
        int idx = bid - 192;
        #pragma unroll 2
        for (int k = 0; k < 16; k++) {
            int b = idx * 64 + w * 16 + k;
            const float* vn = vis_n + (size_t)b * 512 + lane * 8;
            float4 a = *(const float4*)vn, c = *(const float4*)(vn + 4);
            const float* bo = opb + lane * 8;
            float4 b0 = *(const float4*)bo, b1 = *(const float4*)(bo + 4);
            float dt = a.x*b0.x + a.y*b0.y + a.z*b0.z + a.w*b0.w
                     + c.x*b1.x + c.y*b1.y + c.z*b1.z + c.w*b1.w;
            dt = wave_sum(dt);
            if (lane == 0) vb[b] = dt;
        }
        return;
    }

    f32x4 acc[2][2];
    for (int i = 0; i < 2; i++)
        for (int j = 0; j < 2; j++)
            for (int e = 0; e < 4; e++) acc[i][j][e] = 0.f;

    if (bid < 64) {
        // ---- ghead ----
        const int m0 = (bid & 7) * 64, h = bid >> 3;
        stage64x512(u_allb + (size_t)m0 * 4096 + (size_t)h * 512, 4096, As);
        stage64x512(wvb + (size_t)h * 64 * 512, 512, Bs);
        __syncthreads();
        mfma_k512(As, Bs, acc);
        for (int i = 0; i < 2; i++) {
            int row = m0 + wm + i * 16 + quad * 4;
            for (int j = 0; j < 2; j++) {
                int col = wn + j * 16 + l16;
                float bb = bv[h * 64 + col];
                for (int r = 0; r < 4; r++)
                    ctxb[(size_t)(row + r) * 512 + h * 64 + col] = f2bf(acc[i][j][r] + bb);
            }
        }
        return;
    }
    if (bid < 128) {
        // ---- ns_right ----
        const int idx = bid - 64;
        const int m0 = (idx & 7) * 64, n0 = (idx >> 3) * 64;
        stage64x512(vis_nb + (size_t)m0 * 512, 512, As);
        stage64x512(negsb + (size_t)(512 + n0) * 512, 512, Bs);
        __syncthreads();
        mfma_k512(As, Bs, acc);
        for (int i = 0; i < 2; i++) {
            int row = m0 + wm + i * 16 + quad * 4;
            for (int j = 0; j < 2; j++) {
                int col = 512 + n0 + wn + j * 16 + l16;
                for (int r = 0; r < 4; r++)
                    ns[(size_t)(row + r) * 1024 + col] = acc[i][j][r];
            }
        }
        return;
    }
    // ---- G ----
    const int idx = bid - 128;
    const int m0 = (idx & 7) * 64, n0 = (idx >> 3) * 64;
    stage64x512(vis_nb + (size_t)m0 * 512, 512, As);
    stage64x512(woT + (size_t)n0 * 512, 512, Bs);
    __syncthreads();
    mfma_k512(As, Bs, acc);
    for (int i = 0; i < 2; i++) {
        int row = m0 + wm + i * 16 + quad * 4;
        for (int j = 0; j < 2; j++) {
            int col = n0 + wn + j * 16 + l16;
            for (int r = 0; r < 4; r++)
                G[(size_t)(row + r) * 512 + col] = f2bf(acc[i][j][r]);
        }
    }
}

// ---------- K4: tail2 (128 blocks, both halves need only ctxb) ----------
// [0,64):   gcorr: corrected = ctx @ Wo^T + bo (fp32 out + row sumsq)
// [64,128): nsG:   ns[:,0:512] = G @ ctx^T + vb
__global__ __launch_bounds__(256) void tail2(const u16* __restrict__ ctxb,
                                             const u16* __restrict__ wob,
                                             const float* __restrict__ bias,
                                             float* __restrict__ Cf,
                                             float* __restrict__ corrSS,
                                             const u16* __restrict__ G,
                                             const float* __restrict__ vb,
                                             float* __restrict__ ns)
{
    __shared__ __align__(16) u16 As[64 * 520];
    __shared__ __align__(16) u16 Bs[64 * 520];
    const int bid = blockIdx.x;
    const int t = threadIdx.x, lane = t & 63, w = t >> 6;
    const int wm = (w >> 1) * 32, wn = (w & 1) * 32;
    const int l16 = lane & 15, quad = lane >> 4;

    f32x4 acc[2][2];
    for (int i = 0; i < 2; i++)
        for (int j = 0; j < 2; j++)
            for (int e = 0; e < 4; e++) acc[i][j][e] = 0.f;

    if (bid < 64) {
        // ---- gcorr ----
        const int m0 = (bid & 7) * 64, n0 = (bid >> 3) * 64;
        stage64x512(ctxb + (size_t)m0 * 512, 512, As);
        stage64x512(wob + (size_t)n0 * 512, 512, Bs);
        __syncthreads();
        mfma_k512(As, Bs, acc);
        #pragma unroll
        for (int i = 0; i < 2; i++) {
            #pragma unroll
            for (int r = 0; r < 4; r++) {
                int row = m0 + wm + i * 16 + quad * 4 + r;
                float s = 0.f;
                #pragma unroll
                for (int j = 0; j < 2; j++) {
                    int col = n0 + wn + j * 16 + l16;
                    float v = acc[i][j][r] + bias[col];
                    Cf[(size_t)row * 512 + col] = v;
                    s += v * v;
                }
                s += __shfl_xor(s, 1, 64); s += __shfl_xor(s, 2, 64);
                s += __shfl_xor(s, 4, 64); s += __shfl_xor(s, 8, 64);
                if (l16 == 0) atomicAdd(&corrSS[row], s);
            }
        }
        return;
    }

    // ---- nsG: ns[m][n] = G[m] . ctx[n] + vb[m] ----
    const int idx = bid - 64;
    const int m0 = (idx & 7) * 64, n0 = (idx >> 3) * 64;
    stage64x512(G + (size_t)m0 * 512, 512, As);
    stage64x512(ctxb + (size_t)n0 * 512, 512, Bs);
    __syncthreads();
    mfma_k512(As, Bs, acc);
    for (int i = 0; i < 2; i++) {
        int row = m0 + wm + i * 16 + quad * 4;
        for (int j = 0; j < 2; j++) {
            int col = n0 + wn + j * 16 + l16;
            for (int r = 0; r < 4; r++)
                ns[(size_t)(row + r) * 1024 + col] = acc[i][j][r] + vb[row + r];
        }
    }
}

// ---------- K5: top-5 + loss; per-wave top-5 (no sync) then single merge ----------
__global__ __launch_bounds__(256) void topk_loss(const float* __restrict__ ns,
                                                 const float* __restrict__ corrSS,
                                                 const float* __restrict__ tau_p_log,
                                                 const float* __restrict__ tau_n_log,
                                                 float* __restrict__ out_loss)
{
    __shared__ float invn[512];
    __shared__ float cv[20];
    __shared__ int   cjx[20];
    int b = blockIdx.x, t = threadIdx.x;
    int w = t >> 6, lane = t & 63;

    {
        float s0 = corrSS[t], s1 = corrSS[t + 256];
        invn[t]       = 1.0f / fmaxf(sqrtf(s0), EPS);
        invn[t + 256] = 1.0f / fmaxf(sqrtf(s1), EPS);
    }
    __syncthreads();

    const float4 raw = *(const float4*)(ns + (size_t)b * 1024 + t * 4);
    float lv[4] = {raw.x, raw.y, raw.z, raw.w};
    int   li[4] = {t * 4, t * 4 + 1, t * 4 + 2, t * 4 + 3};
    if (t < 128) {
        lv[0] *= invn[t * 4];     lv[1] *= invn[t * 4 + 1];
        lv[2] *= invn[t * 4 + 2]; lv[3] *= invn[t * 4 + 3];
    }
    #pragma unroll
    for (int i = 1; i < 4; i++) {
        float kv = lv[i]; int kx = li[i];
        int j = i - 1;
        #pragma unroll
        for (int k = 0; k < 3; k++) {
            if (j >= 0 && lv[j] < kv) { lv[j + 1] = lv[j]; li[j + 1] = li[j]; j--; }
        }
        lv[j + 1] = kv; li[j + 1] = kx;
    }
    int lp = 0;
    #pragma unroll
    for (int rd = 0; rd < 5; rd++) {
        float mv = (lp < 4) ? lv[lp] : -1e30f;
        int   mi = (lp < 4) ? li[lp] : 0;
        int   ml = lane;
        #pragma unroll
        for (int off = 32; off; off >>= 1) {
            float ov = __shfl_xor(mv, off, 64);
            int   oi = __shfl_xor(mi, off, 64);
            int   ol = __shfl_xor(ml, off, 64);
            if (ov > mv || (ov == mv && ol < ml)) { mv = ov; mi = oi; ml = ol; }
        }
        if (lane == ml) lp++;
        if (lane == 0) { cv[w * 5 + rd] = mv; cjx[w * 5 + rd] = mi; }
    }
    __syncthreads();
    if (w == 0) {
        float v  = (lane < 20) ? cv[lane] : -1e30f;
        int   jx = (lane < 20) ? cjx[lane] : 0;
        float tn = expf(tau_n_log[0]);
        float itn = 1.0f / tn;
        float nsum = 0.f; int coll = 0;
        #pragma unroll
        for (int rd = 0; rd < 5; rd++) {
            float mv = v; int ml = lane; int mj = jx;
            #pragma unroll
            for (int off = 32; off; off >>= 1) {
                float ov = __shfl_xor(mv, off, 64);
                int   oj = __shfl_xor(mj, off, 64);
                int   ol = __shfl_xor(ml, off, 64);
                if (ov > mv || (ov == mv && ol < ml)) { mv = ov; mj = oj; ml = ol; }
            }
            int mult = (mj < 512) ? 2 : 1;
            int take = 5 - coll;
            take = (mult < take) ? mult : take;
            if (take < 0) take = 0;
            nsum += (float)take * __expf(mv * itn);
            coll += take;
            if (lane == ml) v = -1e30f;
        }
        if (lane == 0) {
            float pos = ns[(size_t)b * 1024 + b] * invn[b];   // cos(vis_n, corr_n)
            float tp = expf(tau_p_log[0]);
            float p = expf(pos / tp);
            float term = logf(p / (p + nsum + 1e-8f));
            atomicAdd(out_loss, -term * (1.0f / 512.0f));
        }
    }
}

// ---------- launch ----------
extern "C" void kernel_launch(void* const* d_in, const int* in_sizes, int n_in,
                              void* d_out, int out_size, void* d_ws, size_t ws_size,
                              hipStream_t stream) {
    const float* vis = (const float*)d_in[0];
    const float* tf  = (const float*)d_in[1];
    const float* ipw = (const float*)d_in[2];
    const float* ipb = (const float*)d_in[3];
    const float* opw = (const float*)d_in[4];
    const float* opb = (const float*)d_in[5];
    const float* tm  = (const float*)d_in[6];
    const float* tpl = (const float*)d_in[7];
    const float* tnl = (const float*)d_in[8];

    float* out       = (float*)d_out;
    float* out_loss  = out;
    float* out_corr  = out + 1;                  // (512,512)
    float* out_cs    = out + 1 + 512 * 512;      // (512,3)

    char* p = (char*)d_ws;
    auto alloc = [&](size_t bytes) { char* r = p; p += (bytes + 255) & ~(size_t)255; return r; };
    float* vis_n  = (float*)alloc(512 * 512 * 4);
    u16*   vis_nb = (u16*)  alloc(512 * 512 * 2);
    u16*   wvb    = (u16*)  alloc(512 * 512 * 2);
    u16*   wob    = (u16*)  alloc(512 * 512 * 2);
    u16*   woT    = (u16*)  alloc(512 * 512 * 2);
    u16*   G      = (u16*)  alloc(512 * 512 * 2);
    u16*   qkb    = (u16*)  alloc((size_t)512 * 8 * 512 * 2);
    u16*   u_allb = (u16*)  alloc((size_t)512 * 8 * 512 * 2);
    u16*   ctxb   = (u16*)  alloc(512 * 512 * 2);
    u16*   negsb  = (u16*)  alloc(1024 * 512 * 2);
    float* ns     = (float*)alloc(512 * 1024 * 4);
    float* corrSS = (float*)alloc(512 * 4);
    float* vb     = (float*)alloc(512 * 4);

    const float* bv = ipb + 2 * 512;

    prep<<<896, 256, 0, stream>>>(vis, ipw, opw, tm, ipb, vis_n, vis_nb,
                                  wvb, wob, negsb, woT, qkb, corrSS, out_loss);
    attn<<<512, 1024, 0, stream>>>(tf, vis_n, qkb, u_allb, out_cs);
    gmid<<<200, 256, 0, stream>>>(u_allb, wvb, bv, ctxb, vis_nb, negsb, ns,
                                  woT, G, opb, vb, vis_n);
    tail2<<<128, 256, 0, stream>>>(ctxb, wob, opb, out_corr, corrSS, G, vb, ns);
    topk_loss<<<512, 256, 0, stream>>>(ns, corrSS, tpl, tnl, out_loss);
}

// Round 8
// 233.413 us; speedup vs baseline: 1.0221x; 1.0221x over previous
//
#include <hip/hip_runtime.h>
#include <math.h>

typedef unsigned short u16;
typedef unsigned int u32;
typedef __attribute__((ext_vector_type(8))) short short8;      // 8 bf16 (4 VGPRs) MFMA A/B frag
typedef __attribute__((ext_vector_type(8))) _Float16 half8;    // 8 f16 MFMA A/B frag
typedef __attribute__((ext_vector_type(4))) float f32x4;       // MFMA C/D frag

#define EPS 1e-8f

// ---------- helpers ----------
__device__ inline float bf2f(u16 u) {
    union { u32 i; float f; } v; v.i = ((u32)u) << 16; return v.f;
}
__device__ inline u16 f2bf(float f) {  // RNE
    union { float f; u32 u; } v; v.f = f;
    u32 r = v.u + 0x7fffu + ((v.u >> 16) & 1u);
    return (u16)(r >> 16);
}
__device__ inline u16 f2h(float f) {   // f32 -> f16 RNE
    _Float16 h = (_Float16)f;
    union { _Float16 hh; u16 u; } v; v.hh = h; return v.u;
}
__device__ inline u32 pack2(float a, float b) {
    return (u32)f2bf(a) | ((u32)f2bf(b) << 16);
}
__device__ inline float wave_sum(float v) {
    for (int off = 32; off; off >>= 1) v += __shfl_xor(v, off, 64);
    return v;
}

// ---- single-phase 64x64 tile, K=512: stage whole 64x512 into LDS (stride 520) ----
__device__ __forceinline__ void stage64x512(const u16* __restrict__ Ag, size_t lda,
                                            u16* __restrict__ As) {
    const int t = threadIdx.x;
    const int srow = t >> 2;
    const int c0 = (t & 3) * 8;
    #pragma unroll
    for (int kk = 0; kk < 16; kk++) {
        int c = c0 + kk * 32;
        *(uint4*)&As[srow * 520 + c] = *(const uint4*)&Ag[(size_t)srow * lda + c];
    }
}
__device__ __forceinline__ void mfma_k512(const u16* __restrict__ As,
                                          const u16* __restrict__ Bs,
                                          f32x4 (&acc)[2][2]) {
    const int t = threadIdx.x, lane = t & 63, w = t >> 6;
    const int wm = (w >> 1) * 32, wn = (w & 1) * 32;
    const int l16 = lane & 15, quad = lane >> 4;
    #pragma unroll
    for (int ks = 0; ks < 16; ks++) {
        short8 af[2], bfr[2];
        #pragma unroll
        for (int i = 0; i < 2; i++)
            af[i] = *(const short8*)&As[(wm + i * 16 + l16) * 520 + ks * 32 + quad * 8];
        #pragma unroll
        for (int j = 0; j < 2; j++)
            bfr[j] = *(const short8*)&Bs[(wn + j * 16 + l16) * 520 + ks * 32 + quad * 8];
        #pragma unroll
        for (int i = 0; i < 2; i++)
            #pragma unroll
            for (int j = 0; j < 2; j++)
                acc[i][j] = __builtin_amdgcn_mfma_f32_16x16x32_bf16(af[i], bfr[j], acc[i][j], 0, 0, 0);
    }
}

// ---------- K1: prep (includes self-contained qqk) ----------
// [0,64):    qqk: q-proj + qk-proj from raw fp32 inputs -> qkb bf16
// [64,192):  vis rows: fp32-norm + bf16-norm (+ zero loss/corrSS in bid 64)
// [192,448): wv cvt -> bf16
// [448,704): wo cvt -> bf16
// [704,832): tm rows -> normalized bf16 negsb[512:]
// [832,896): wo -> transposed bf16 woT[c][j]
__global__ __launch_bounds__(256) void prep(const float* __restrict__ vis,
                                            const float* __restrict__ ipw,
                                            const float* __restrict__ opw,
                                            const float* __restrict__ tm,
                                            const float* __restrict__ ipb,
                                            float* __restrict__ vis_n,
                                            u16* __restrict__ vis_nb,
                                            u16* __restrict__ wvb,
                                            u16* __restrict__ wob,
                                            u16* __restrict__ negsb,
                                            u16* __restrict__ woT,
                                            u16* __restrict__ qkb,
                                            float* __restrict__ corrSS,
                                            float* __restrict__ loss0)
{
    __shared__ __align__(16) u16 SMEM[3 * 64 * 72];   // 27648 B (qqk: As|Bs|Qf; transposes: T)
    int bid = blockIdx.x;
    int t = threadIdx.x;
    if (bid >= 832) {                        // wo transpose -> bf16 woT[c][j]
        u16* T = SMEM;
        int idx = bid - 832;
        int a = idx >> 3, cb = idx & 7;
        int r = t >> 2, c0 = (t & 3) * 16;
        #pragma unroll
        for (int q = 0; q < 4; q++) {
            float4 v = *(const float4*)&opw[(size_t)(a * 64 + r) * 512 + cb * 64 + c0 + q * 4];
            T[(c0 + q * 4 + 0) * 72 + r] = f2bf(v.x);
            T[(c0 + q * 4 + 1) * 72 + r] = f2bf(v.y);
            T[(c0 + q * 4 + 2) * 72 + r] = f2bf(v.z);
            T[(c0 + q * 4 + 3) * 72 + r] = f2bf(v.w);
        }
        __syncthreads();
        int j = t >> 2, ch = (t & 3) * 16;
        *(uint4*)&woT[(size_t)(cb * 64 + j) * 512 + a * 64 + ch]     = *(const uint4*)&T[j * 72 + ch];
        *(uint4*)&woT[(size_t)(cb * 64 + j) * 512 + a * 64 + ch + 8] = *(const uint4*)&T[j * 72 + ch + 8];
        return;
    }
    if (bid >= 704) {                        // tm rows -> normalized negsb[512:]
        int wave = t >> 6, lane = t & 63;
        int j = 512 + (bid - 704) * 4 + wave;
        const float* row = tm + (size_t)(j - 512) * 512 + lane * 8;
        float4 x0 = *(const float4*)row;
        float4 x1 = *(const float4*)(row + 4);
        float ss = x0.x*x0.x + x0.y*x0.y + x0.z*x0.z + x0.w*x0.w
                 + x1.x*x1.x + x1.y*x1.y + x1.z*x1.z + x1.w*x1.w;
        ss = wave_sum(ss);
        float inv = 1.0f / fmaxf(sqrtf(ss), EPS);
        uint4 pk;
        pk.x = pack2(x0.x*inv, x0.y*inv); pk.y = pack2(x0.z*inv, x0.w*inv);
        pk.z = pack2(x1.x*inv, x1.y*inv); pk.w = pack2(x1.z*inv, x1.w*inv);
        *(uint4*)(negsb + (size_t)j * 512 + lane * 8) = pk;
        return;
    }
    if (bid >= 448) {                        // wo cvt
        int i = (bid - 448) * 1024 + t * 4;
        float4 v = *(const float4*)(opw + i);
        uint2 pk; pk.x = pack2(v.x, v.y); pk.y = pack2(v.z, v.w);
        *(uint2*)(wob + i) = pk;
        return;
    }
    if (bid >= 192) {                        // wv cvt
        int i = (bid - 192) * 1024 + t * 4;
        float4 v = *(const float4*)(ipw + 524288 + i);
        uint2 pk; pk.x = pack2(v.x, v.y); pk.y = pack2(v.z, v.w);
        *(uint2*)(wvb + i) = pk;
        return;
    }
    if (bid >= 64) {                         // vis rows
        if (bid == 64) {
            if (t == 0) loss0[0] = 0.0f;
            corrSS[t] = 0.0f;
            corrSS[t + 256] = 0.0f;
        }
        int wave = t >> 6, lane = t & 63;
        int b = (bid - 64) * 4 + wave;       // B = 512
        const float* row = vis + (size_t)b * 512 + lane * 8;
        float4 x0 = *(const float4*)row;
        float4 x1 = *(const float4*)(row + 4);
        float ss = x0.x*x0.x + x0.y*x0.y + x0.z*x0.z + x0.w*x0.w
                 + x1.x*x1.x + x1.y*x1.y + x1.z*x1.z + x1.w*x1.w;
        ss = wave_sum(ss);
        float inv = 1.0f / fmaxf(sqrtf(ss), EPS);
        float4 y0, y1;
        y0.x = x0.x*inv; y0.y = x0.y*inv; y0.z = x0.z*inv; y0.w = x0.w*inv;
        y1.x = x1.x*inv; y1.y = x1.y*inv; y1.z = x1.z*inv; y1.w = x1.w*inv;
        *(float4*)(vis_n + (size_t)b * 512 + lane * 8)     = y0;
        *(float4*)(vis_n + (size_t)b * 512 + lane * 8 + 4) = y1;
        uint4 pk;
        pk.x = pack2(y0.x, y0.y); pk.y = pack2(y0.z, y0.w);
        pk.z = pack2(y1.x, y1.y); pk.w = pack2(y1.z, y1.w);
        *(uint4*)(vis_nb + (size_t)b * 512 + lane * 8) = pk;
        return;
    }

    // ---- qqk: 64 blocks, self-contained from fp32 inputs ----
    u16* As = SMEM;              // 64x72 bf16
    u16* Bs = SMEM + 4608;       // 64x72
    u16* Qf = SMEM + 9216;       // 64x72 f16
    const int lane = t & 63, w = t >> 6;
    const int wm = (w >> 1) * 32, wn = (w & 1) * 32;
    const int l16 = lane & 15, quad = lane >> 4;
    const int srow = t >> 3, scol = (t & 7) * 8;
    const int m0 = (bid & 7) * 64, h = bid >> 3;
    const float* wkf = ipw + 262144;         // wk fp32 rows

    f32x4 acc[2][2];
    for (int i = 0; i < 2; i++)
        for (int j = 0; j < 2; j++)
            for (int e = 0; e < 4; e++) acc[i][j][e] = 0.f;

    for (int ko = 0; ko < 512; ko += 64) {
        __syncthreads();
        #pragma unroll
        for (int i = 0; i < 2; i++) {
            int row = i * 32 + srow;
            const float* ap = vis + (size_t)(m0 + row) * 512 + ko + scol;
            float4 a0 = *(const float4*)ap, a1 = *(const float4*)(ap + 4);
            uint4 pkA;
            pkA.x = pack2(a0.x, a0.y); pkA.y = pack2(a0.z, a0.w);
            pkA.z = pack2(a1.x, a1.y); pkA.w = pack2(a1.z, a1.w);
            *(uint4*)&As[row * 72 + scol] = pkA;
            const float* bp = ipw + (size_t)(h * 64 + row) * 512 + ko + scol;
            float4 b0 = *(const float4*)bp, b1 = *(const float4*)(bp + 4);
            uint4 pkB;
            pkB.x = pack2(b0.x, b0.y); pkB.y = pack2(b0.z, b0.w);
            pkB.z = pack2(b1.x, b1.y); pkB.w = pack2(b1.z, b1.w);
            *(uint4*)&Bs[row * 72 + scol] = pkB;
        }
        __syncthreads();
        #pragma unroll
        for (int ks = 0; ks < 2; ks++) {
            short8 af[2], bfr[2];
            #pragma unroll
            for (int i = 0; i < 2; i++)
                af[i] = *(const short8*)&As[(wm + i * 16 + l16) * 72 + ks * 32 + quad * 8];
            #pragma unroll
            for (int j = 0; j < 2; j++)
                bfr[j] = *(const short8*)&Bs[(wn + j * 16 + l16) * 72 + ks * 32 + quad * 8];
            #pragma unroll
            for (int i = 0; i < 2; i++)
                #pragma unroll
                for (int j = 0; j < 2; j++)
                    acc[i][j] = __builtin_amdgcn_mfma_f32_16x16x32_bf16(af[i], bfr[j], acc[i][j], 0, 0, 0);
        }
    }
    // epilogue: q (+bq) -> f16 in Qf
    #pragma unroll
    for (int i = 0; i < 2; i++)
        #pragma unroll
        for (int j = 0; j < 2; j++)
            #pragma unroll
            for (int r = 0; r < 4; r++) {
                int rl = wm + i * 16 + quad * 4 + r;
                int cl = wn + j * 16 + l16;
                Qf[rl * 72 + cl] = f2h(acc[i][j][r] + ipb[h * 64 + cl]);
            }
    // Phase B: per jt, inline transpose wk fp32 tile -> f16 Bs[j][d]
    for (int jt = 0; jt < 8; jt++) {
        __syncthreads();
        {
            int r = t >> 2, c0 = (t & 3) * 16;
            #pragma unroll
            for (int q = 0; q < 4; q++) {
                float4 v = *(const float4*)&wkf[(size_t)(h * 64 + r) * 512 + jt * 64 + c0 + q * 4];
                Bs[(c0 + q * 4 + 0) * 72 + r] = f2h(v.x);
                Bs[(c0 + q * 4 + 1) * 72 + r] = f2h(v.y);
                Bs[(c0 + q * 4 + 2) * 72 + r] = f2h(v.z);
                Bs[(c0 + q * 4 + 3) * 72 + r] = f2h(v.w);
            }
        }
        __syncthreads();
        f32x4 a2[2][2];
        for (int i = 0; i < 2; i++)
            for (int j = 0; j < 2; j++)
                for (int e = 0; e < 4; e++) a2[i][j][e] = 0.f;
        #pragma unroll
        for (int ks = 0; ks < 2; ks++) {
            half8 af[2], bfr[2];
            #pragma unroll
            for (int i = 0; i < 2; i++)
                af[i] = *(const half8*)&Qf[(wm + i * 16 + l16) * 72 + ks * 32 + quad * 8];
            #pragma unroll
            for (int j = 0; j < 2; j++)
                bfr[j] = *(const half8*)&Bs[(wn + j * 16 + l16) * 72 + ks * 32 + quad * 8];
            #pragma unroll
            for (int i = 0; i < 2; i++)
                #pragma unroll
                for (int j = 0; j < 2; j++)
                    a2[i][j] = __builtin_amdgcn_mfma_f32_16x16x32_f16(af[i], bfr[j], a2[i][j], 0, 0, 0);
        }
        #pragma unroll
        for (int i = 0; i < 2; i++)
            #pragma unroll
            for (int j = 0; j < 2; j++)
                #pragma unroll
                for (int r = 0; r < 4; r++) {
                    int rb = m0 + wm + i * 16 + quad * 4 + r;
                    int cj = jt * 64 + wn + j * 16 + l16;
                    qkb[((size_t)rb * 8 + h) * 512 + cj] = f2bf(a2[i][j][r]);
                }
    }
}

// ---------- K2: attention (fused tf stream, ROUND-6 proven load schedule); 512 x 1024 ----------
__global__ __launch_bounds__(1024) void attn(const float* __restrict__ tf,
                                             const float* __restrict__ vis_n,
                                             const u16* __restrict__ qkb,
                                             u16* __restrict__ u_allb,
                                             float* __restrict__ out_cs)
{
    __shared__ __align__(16) u16 Xs[96 * 520];
    __shared__ __align__(16) u16 Qs[16 * 520];
    __shared__ __align__(16) u16 Ps[16 * 104];
    __shared__ float Sc[16 * 100];
    __shared__ float sm_[96], srt[96], linv[8];

    const int b = blockIdx.x;
    const int t = threadIdx.x, w = t >> 6, lane = t & 63;
    const int l16 = lane & 15, quad = lane >> 4;

    const float4* v4 = (const float4*)(vis_n + (size_t)b * 512 + lane * 8);
    float4 va = v4[0], vbv = v4[1];

    // stream 96 fp32 rows: wave w owns rows w+16k; 3 iters x 2 rows for shuffle ILP
    #pragma unroll
    for (int i = 0; i < 3; i++) {
        int m0r = w + i * 32;
        int m1r = m0r + 16;
        const float4* pa = (const float4*)(tf + ((size_t)b * 96 + m0r) * 512 + lane * 8);
        const float4* pb = (const float4*)(tf + ((size_t)b * 96 + m1r) * 512 + lane * 8);
        float4 a0 = pa[0], c0 = pa[1];
        float4 a1 = pb[0], c1 = pb[1];
        float ss0 = a0.x*a0.x + a0.y*a0.y + a0.z*a0.z + a0.w*a0.w
                  + c0.x*c0.x + c0.y*c0.y + c0.z*c0.z + c0.w*c0.w;
        float dt0 = a0.x*va.x + a0.y*va.y + a0.z*va.z + a0.w*va.w
                  + c0.x*vbv.x + c0.y*vbv.y + c0.z*vbv.z + c0.w*vbv.w;
        float ss1 = a1.x*a1.x + a1.y*a1.y + a1.z*a1.z + a1.w*a1.w
                  + c1.x*c1.x + c1.y*c1.y + c1.z*c1.z + c1.w*c1.w;
        float dt1 = a1.x*va.x + a1.y*va.y + a1.z*va.z + a1.w*va.w
                  + c1.x*vbv.x + c1.y*vbv.y + c1.z*vbv.z + c1.w*vbv.w;
        #pragma unroll
        for (int off = 32; off; off >>= 1) {
            ss0 += __shfl_xor(ss0, off, 64);
            dt0 += __shfl_xor(dt0, off, 64);
            ss1 += __shfl_xor(ss1, off, 64);
            dt1 += __shfl_xor(dt1, off, 64);
        }
        if (lane == 0) {
            sm_[m0r] = dt0 / fmaxf(sqrtf(ss0), EPS);
            sm_[m1r] = dt1 / fmaxf(sqrtf(ss1), EPS);
        }
        uint4 pk0, pk1;
        pk0.x = pack2(a0.x, a0.y); pk0.y = pack2(a0.z, a0.w);
        pk0.z = pack2(c0.x, c0.y); pk0.w = pack2(c0.z, c0.w);
        pk1.x = pack2(a1.x, a1.y); pk1.y = pack2(a1.z, a1.w);
        pk1.z = pack2(c1.x, c1.y); pk1.w = pack2(c1.z, c1.w);
        *(uint4*)&Xs[m0r * 520 + lane * 8] = pk0;
        *(uint4*)&Xs[m1r * 520 + lane * 8] = pk1;
    }
    if (w < 8) {
        *(uint4*)&Qs[w * 520 + lane * 8] = *(const uint4*)(qkb + ((size_t)b * 8 + w) * 512 + lane * 8);
    } else {
        uint4 z; z.x = 0; z.y = 0; z.z = 0; z.w = 0;
        *(uint4*)&Qs[w * 520 + lane * 8] = z;
    }
    __syncthreads();

    if (w < 6) {
        f32x4 acc;
        for (int e = 0; e < 4; e++) acc[e] = 0.f;
        #pragma unroll
        for (int ks = 0; ks < 16; ks++) {
            short8 a = *(const short8*)&Xs[(w * 16 + l16) * 520 + ks * 32 + quad * 8];
            short8 q = *(const short8*)&Qs[l16 * 520 + ks * 32 + quad * 8];
            acc = __builtin_amdgcn_mfma_f32_16x16x32_bf16(a, q, acc, 0, 0, 0);
        }
        #pragma unroll
        for (int r = 0; r < 4; r++)
            Sc[l16 * 100 + w * 16 + quad * 4 + r] = acc[r] * 0.125f;
    }
    __syncthreads();

    if (w < 8) {
        float e0 = __expf(Sc[w * 100 + lane]);
        float e1 = (lane < 32) ? __expf(Sc[w * 100 + 64 + lane]) : 0.f;
        float l = wave_sum(e0 + e1);
        Ps[w * 104 + lane] = f2bf(e0);
        if (lane < 32) Ps[w * 104 + 64 + lane] = f2bf(e1);
        if (lane == 0) linv[w] = 1.0f / l;
    } else {
        Ps[w * 104 + lane] = 0;
        if (lane < 40) Ps[w * 104 + 64 + lane] = 0;
    }
    if (t < 96) {
        float v = sm_[t]; int r = 0;
        for (int j = 0; j < 96; j++) {
            float u = sm_[j];
            r += (u > v) || (u == v && j < t);
        }
        srt[r] = v;
    }
    __syncthreads();

    #pragma unroll
    for (int jj = 0; jj < 2; jj++) {
        int n0 = (w * 2 + jj) * 16;
        f32x4 acc;
        for (int e = 0; e < 4; e++) acc[e] = 0.f;
        #pragma unroll
        for (int ks = 0; ks < 3; ks++) {
            short8 ap = *(const short8*)&Ps[l16 * 104 + ks * 32 + quad * 8];
            short8 bx;
            #pragma unroll
            for (int j = 0; j < 8; j++)
                bx[j] = (short)Xs[(ks * 32 + quad * 8 + j) * 520 + n0 + l16];
            acc = __builtin_amdgcn_mfma_f32_16x16x32_bf16(ap, bx, acc, 0, 0, 0);
        }
        if (quad < 2) {
            #pragma unroll
            for (int r = 0; r < 4; r++) {
                int h = quad * 4 + r;
                u_allb[((size_t)b * 8 + h) * 512 + n0 + l16] = f2bf(acc[r] * linv[h]);
            }
        }
    }
    if (t < 3) {
        float mean = 0.f;
        #pragma unroll 8
        for (int i = 0; i < 32; i++) mean += srt[t * 32 + i];
        mean *= (1.0f / 32.0f);
        float var = 0.f;
        #pragma unroll 8
        for (int i = 0; i < 32; i++) { float d = srt[t * 32 + i] - mean; var += d * d; }
        var *= (1.0f / 31.0f);
        out_cs[b * 3 + t] = mean / (sqrtf(var) + 1e-6f);
    }
}

// ---------- K3: gmid (200 blocks, all independent, single-phase K=512) ----------
// [0,64):    ghead: ctx_h = u_h @ Wv_h^T + bv_h -> ctxb bf16
// [64,128):  ns_right: ns[:,512:1024] = vis_nb @ negsb[512:]^T
// [128,192): G = vis_nb @ woT^T (bf16)
// [192,200): vb[b] = vis_n[b] . bo
__global__ __launch_bounds__(256) void gmid(const u16* __restrict__ u_allb,
                                            const u16* __restrict__ wvb,
                                            const float* __restrict__ bv,
                                            u16* __restrict__ ctxb,
                                            const u16* __restrict__ vis_nb,
                                            const u16* __restrict__ negsb,
                                            float* __restrict__ ns,
                                            const u16* __restrict__ woT,
                                            u16* __restrict__ G,
                                            const float* __restrict__ opb,
                                            float* __restrict__ vb,
                                            const float* __restrict__ vis_n)
{
    __shared__ __align__(16) u16 As[64 * 520];
    __shared__ __align__(16) u16 Bs[64 * 520];
    const int bid = blockIdx.x;
    const int t = threadIdx.x, lane = t & 63, w = t >> 6;
    const int wm = (w >> 1) * 32, wn = (w & 1) * 32;
    const int l16 = lane & 15, quad = lane >> 4;

    if (bid >= 192) {
        // ---- vb: 8 blocks x 4 waves x 16 b ----
        int idx = bid - 192;
        #pragma unroll 2
        for (int k = 0; k < 16; k++) {
            int b = idx * 64 + w * 16 + k;
            const float* vn = vis_n + (size_t)b * 512 + lane * 8;
            float4 a = *(const float4*)vn, c = *(const float4*)(vn + 4);
            const float* bo = opb + lane * 8;
            float4 b0 = *(const float4*)bo, b1 = *(const float4*)(bo + 4);
            float dt = a.x*b0.x + a.y*b0.y + a.z*b0.z + a.w*b0.w
                     + c.x*b1.x + c.y*b1.y + c.z*b1.z + c.w*b1.w;
            dt = wave_sum(dt);
            if (lane == 0) vb[b] = dt;
        }
        return;
    }

    f32x4 acc[2][2];
    for (int i = 0; i < 2; i++)
        for (int j = 0; j < 2; j++)
            for (int e = 0; e < 4; e++) acc[i][j][e] = 0.f;

    if (bid < 64) {
        // ---- ghead ----
        const int m0 = (bid & 7) * 64, h = bid >> 3;
        stage64x512(u_allb + (size_t)m0 * 4096 + (size_t)h * 512, 4096, As);
        stage64x512(wvb + (size_t)h * 64 * 512, 512, Bs);
        __syncthreads();
        mfma_k512(As, Bs, acc);
        for (int i = 0; i < 2; i++) {
            int row = m0 + wm + i * 16 + quad * 4;
            for (int j = 0; j < 2; j++) {
                int col = wn + j * 16 + l16;
                float bb = bv[h * 64 + col];
                for (int r = 0; r < 4; r++)
                    ctxb[(size_t)(row + r) * 512 + h * 64 + col] = f2bf(acc[i][j][r] + bb);
            }
        }
        return;
    }
    if (bid < 128) {
        // ---- ns_right ----
        const int idx = bid - 64;
        const int m0 = (idx & 7) * 64, n0 = (idx >> 3) * 64;
        stage64x512(vis_nb + (size_t)m0 * 512, 512, As);
        stage64x512(negsb + (size_t)(512 + n0) * 512, 512, Bs);
        __syncthreads();
        mfma_k512(As, Bs, acc);
        for (int i = 0; i < 2; i++) {
            int row = m0 + wm + i * 16 + quad * 4;
            for (int j = 0; j < 2; j++) {
                int col = 512 + n0 + wn + j * 16 + l16;
                for (int r = 0; r < 4; r++)
                    ns[(size_t)(row + r) * 1024 + col] = acc[i][j][r];
            }
        }
        return;
    }
    // ---- G ----
    const int idx = bid - 128;
    const int m0 = (idx & 7) * 64, n0 = (idx >> 3) * 64;
    stage64x512(vis_nb + (size_t)m0 * 512, 512, As);
    stage64x512(woT + (size_t)n0 * 512, 512, Bs);
    __syncthreads();
    mfma_k512(As, Bs, acc);
    for (int i = 0; i < 2; i++) {
        int row = m0 + wm + i * 16 + quad * 4;
        for (int j = 0; j < 2; j++) {
            int col = n0 + wn + j * 16 + l16;
            for (int r = 0; r < 4; r++)
                G[(size_t)(row + r) * 512 + col] = f2bf(acc[i][j][r]);
        }
    }
}

// ---------- K4: tail2 (128 blocks, both halves need only ctxb) ----------
// [0,64):   gcorr: corrected = ctx @ Wo^T + bo (fp32 out + row sumsq)
// [64,128): nsG:   ns[:,0:512] = G @ ctx^T + vb
__global__ __launch_bounds__(256) void tail2(const u16* __restrict__ ctxb,
                                             const u16* __restrict__ wob,
                                             const float* __restrict__ bias,
                                             float* __restrict__ Cf,
                                             float* __restrict__ corrSS,
                                             const u16* __restrict__ G,
                                             const float* __restrict__ vb,
                                             float* __restrict__ ns)
{
    __shared__ __align__(16) u16 As[64 * 520];
    __shared__ __align__(16) u16 Bs[64 * 520];
    const int bid = blockIdx.x;
    const int t = threadIdx.x, lane = t & 63, w = t >> 6;
    const int wm = (w >> 1) * 32, wn = (w & 1) * 32;
    const int l16 = lane & 15, quad = lane >> 4;

    f32x4 acc[2][2];
    for (int i = 0; i < 2; i++)
        for (int j = 0; j < 2; j++)
            for (int e = 0; e < 4; e++) acc[i][j][e] = 0.f;

    if (bid < 64) {
        // ---- gcorr ----
        const int m0 = (bid & 7) * 64, n0 = (bid >> 3) * 64;
        stage64x512(ctxb + (size_t)m0 * 512, 512, As);
        stage64x512(wob + (size_t)n0 * 512, 512, Bs);
        __syncthreads();
        mfma_k512(As, Bs, acc);
        #pragma unroll
        for (int i = 0; i < 2; i++) {
            #pragma unroll
            for (int r = 0; r < 4; r++) {
                int row = m0 + wm + i * 16 + quad * 4 + r;
                float s = 0.f;
                #pragma unroll
                for (int j = 0; j < 2; j++) {
                    int col = n0 + wn + j * 16 + l16;
                    float v = acc[i][j][r] + bias[col];
                    Cf[(size_t)row * 512 + col] = v;
                    s += v * v;
                }
                s += __shfl_xor(s, 1, 64); s += __shfl_xor(s, 2, 64);
                s += __shfl_xor(s, 4, 64); s += __shfl_xor(s, 8, 64);
                if (l16 == 0) atomicAdd(&corrSS[row], s);
            }
        }
        return;
    }

    // ---- nsG: ns[m][n] = G[m] . ctx[n] + vb[m] ----
    const int idx = bid - 64;
    const int m0 = (idx & 7) * 64, n0 = (idx >> 3) * 64;
    stage64x512(G + (size_t)m0 * 512, 512, As);
    stage64x512(ctxb + (size_t)n0 * 512, 512, Bs);
    __syncthreads();
    mfma_k512(As, Bs, acc);
    for (int i = 0; i < 2; i++) {
        int row = m0 + wm + i * 16 + quad * 4;
        for (int j = 0; j < 2; j++) {
            int col = n0 + wn + j * 16 + l16;
            for (int r = 0; r < 4; r++)
                ns[(size_t)(row + r) * 1024 + col] = acc[i][j][r] + vb[row + r];
        }
    }
}

// ---------- K5: top-5 + loss; per-wave top-5 (no sync) then single merge ----------
__global__ __launch_bounds__(256) void topk_loss(const float* __restrict__ ns,
                                                 const float* __restrict__ corrSS,
                                                 const float* __restrict__ tau_p_log,
                                                 const float* __restrict__ tau_n_log,
                                                 float* __restrict__ out_loss)
{
    __shared__ float invn[512];
    __shared__ float cv[20];
    __shared__ int   cjx[20];
    int b = blockIdx.x, t = threadIdx.x;
    int w = t >> 6, lane = t & 63;

    {
        float s0 = corrSS[t], s1 = corrSS[t + 256];
        invn[t]       = 1.0f / fmaxf(sqrtf(s0), EPS);
        invn[t + 256] = 1.0f / fmaxf(sqrtf(s1), EPS);
    }
    __syncthreads();

    const float4 raw = *(const float4*)(ns + (size_t)b * 1024 + t * 4);
    float lv[4] = {raw.x, raw.y, raw.z, raw.w};
    int   li[4] = {t * 4, t * 4 + 1, t * 4 + 2, t * 4 + 3};
    if (t < 128) {
        lv[0] *= invn[t * 4];     lv[1] *= invn[t * 4 + 1];
        lv[2] *= invn[t * 4 + 2]; lv[3] *= invn[t * 4 + 3];
    }
    #pragma unroll
    for (int i = 1; i < 4; i++) {
        float kv = lv[i]; int kx = li[i];
        int j = i - 1;
        #pragma unroll
        for (int k = 0; k < 3; k++) {
            if (j >= 0 && lv[j] < kv) { lv[j + 1] = lv[j]; li[j + 1] = li[j]; j--; }
        }
        lv[j + 1] = kv; li[j + 1] = kx;
    }
    int lp = 0;
    #pragma unroll
    for (int rd = 0; rd < 5; rd++) {
        float mv = (lp < 4) ? lv[lp] : -1e30f;
        int   mi = (lp < 4) ? li[lp] : 0;
        int   ml = lane;
        #pragma unroll
        for (int off = 32; off; off >>= 1) {
            float ov = __shfl_xor(mv, off, 64);
            int   oi = __shfl_xor(mi, off, 64);
            int   ol = __shfl_xor(ml, off, 64);
            if (ov > mv || (ov == mv && ol < ml)) { mv = ov; mi = oi; ml = ol; }
        }
        if (lane == ml) lp++;
        if (lane == 0) { cv[w * 5 + rd] = mv; cjx[w * 5 + rd] = mi; }
    }
    __syncthreads();
    if (w == 0) {
        float v  = (lane < 20) ? cv[lane] : -1e30f;
        int   jx = (lane < 20) ? cjx[lane] : 0;
        float tn = expf(tau_n_log[0]);
        float itn = 1.0f / tn;
        float nsum = 0.f; int coll = 0;
        #pragma unroll
        for (int rd = 0; rd < 5; rd++) {
            float mv = v; int ml = lane; int mj = jx;
            #pragma unroll
            for (int off = 32; off; off >>= 1) {
                float ov = __shfl_xor(mv, off, 64);
                int   oj = __shfl_xor(mj, off, 64);
                int   ol = __shfl_xor(ml, off, 64);
                if (ov > mv || (ov == mv && ol < ml)) { mv = ov; mj = oj; ml = ol; }
            }
            int mult = (mj < 512) ? 2 : 1;
            int take = 5 - coll;
            take = (mult < take) ? mult : take;
            if (take < 0) take = 0;
            nsum += (float)take * __expf(mv * itn);
            coll += take;
            if (lane == ml) v = -1e30f;
        }
        if (lane == 0) {
            float pos = ns[(size_t)b * 1024 + b] * invn[b];   // cos(vis_n, corr_n)
            float tp = expf(tau_p_log[0]);
            float p = expf(pos / tp);
            float term = logf(p / (p + nsum + 1e-8f));
            atomicAdd(out_loss, -term * (1.0f / 512.0f));
        }
    }
}

// ---------- launch ----------
extern "C" void kernel_launch(void* const* d_in, const int* in_sizes, int n_in,
                              void* d_out, int out_size, void* d_ws, size_t ws_size,
                              hipStream_t stream) {
    const float* vis = (const float*)d_in[0];
    const float* tf  = (const float*)d_in[1];
    const float* ipw = (const float*)d_in[2];
    const float* ipb = (const float*)d_in[3];
    const float* opw = (const float*)d_in[4];
    const float* opb = (const float*)d_in[5];
    const float* tm  = (const float*)d_in[6];
    const float* tpl = (const float*)d_in[7];
    const float* tnl = (const float*)d_in[8];

    float* out       = (float*)d_out;
    float* out_loss  = out;
    float* out_corr  = out + 1;                  // (512,512)
    float* out_cs    = out + 1 + 512 * 512;      // (512,3)

    char* p = (char*)d_ws;
    auto alloc = [&](size_t bytes) { char* r = p; p += (bytes + 255) & ~(size_t)255; return r; };
    float* vis_n  = (float*)alloc(512 * 512 * 4);
    u16*   vis_nb = (u16*)  alloc(512 * 512 * 2);
    u16*   wvb    = (u16*)  alloc(512 * 512 * 2);
    u16*   wob    = (u16*)  alloc(512 * 512 * 2);
    u16*   woT    = (u16*)  alloc(512 * 512 * 2);
    u16*   G      = (u16*)  alloc(512 * 512 * 2);
    u16*   qkb    = (u16*)  alloc((size_t)512 * 8 * 512 * 2);
    u16*   u_allb = (u16*)  alloc((size_t)512 * 8 * 512 * 2);
    u16*   ctxb   = (u16*)  alloc(512 * 512 * 2);
    u16*   negsb  = (u16*)  alloc(1024 * 512 * 2);
    float* ns     = (float*)alloc(512 * 1024 * 4);
    float* corrSS = (float*)alloc(512 * 4);
    float* vb     = (float*)alloc(512 * 4);

    const float* bv = ipb + 2 * 512;

    prep<<<896, 256, 0, stream>>>(vis, ipw, opw, tm, ipb, vis_n, vis_nb,
                                  wvb, wob, negsb, woT, qkb, corrSS, out_loss);
    attn<<<512, 1024, 0, stream>>>(tf, vis_n, qkb, u_allb, out_cs);
    gmid<<<200, 256, 0, stream>>>(u_allb, wvb, bv, ctxb, vis_nb, negsb, ns,
                                  woT, G, opb, vb, vis_n);
    tail2<<<128, 256, 0, stream>>>(ctxb, wob, opb, out_corr, corrSS, G, vb, ns);
    topk_loss<<<512, 256, 0, stream>>>(ns, corrSS, tpl, tnl, out_loss);
}

// Round 9
// 220.093 us; speedup vs baseline: 1.0839x; 1.0605x over previous
//
#include <hip/hip_runtime.h>
#include <math.h>

typedef unsigned short u16;
typedef unsigned int u32;
typedef __attribute__((ext_vector_type(8))) short short8;      // 8 bf16 (4 VGPRs) MFMA A/B frag
typedef __attribute__((ext_vector_type(8))) _Float16 half8;    // 8 f16 MFMA A/B frag
typedef __attribute__((ext_vector_type(4))) float f32x4;       // MFMA C/D frag

#define EPS 1e-8f

// ---------- helpers ----------
__device__ inline float bf2f(u16 u) {
    union { u32 i; float f; } v; v.i = ((u32)u) << 16; return v.f;
}
__device__ inline u16 f2bf(float f) {  // RNE
    union { float f; u32 u; } v; v.f = f;
    u32 r = v.u + 0x7fffu + ((v.u >> 16) & 1u);
    return (u16)(r >> 16);
}
__device__ inline u16 f2h(float f) {   // f32 -> f16 RNE
    _Float16 h = (_Float16)f;
    union { _Float16 hh; u16 u; } v; v.hh = h; return v.u;
}
__device__ inline u32 pack2(float a, float b) {
    return (u32)f2bf(a) | ((u32)f2bf(b) << 16);
}
__device__ inline float wave_sum(float v) {
    for (int off = 32; off; off >>= 1) v += __shfl_xor(v, off, 64);
    return v;
}

// ---- single-phase 64x64 tile, K=512: stage whole 64x512 into LDS (stride 520) ----
__device__ __forceinline__ void stage64x512(const u16* __restrict__ Ag, size_t lda,
                                            u16* __restrict__ As) {
    const int t = threadIdx.x;
    const int srow = t >> 2;
    const int c0 = (t & 3) * 8;
    #pragma unroll
    for (int kk = 0; kk < 16; kk++) {
        int c = c0 + kk * 32;
        *(uint4*)&As[srow * 520 + c] = *(const uint4*)&Ag[(size_t)srow * lda + c];
    }
}
__device__ __forceinline__ void mfma_k512(const u16* __restrict__ As,
                                          const u16* __restrict__ Bs,
                                          f32x4 (&acc)[2][2]) {
    const int t = threadIdx.x, lane = t & 63, w = t >> 6;
    const int wm = (w >> 1) * 32, wn = (w & 1) * 32;
    const int l16 = lane & 15, quad = lane >> 4;
    #pragma unroll
    for (int ks = 0; ks < 16; ks++) {
        short8 af[2], bfr[2];
        #pragma unroll
        for (int i = 0; i < 2; i++)
            af[i] = *(const short8*)&As[(wm + i * 16 + l16) * 520 + ks * 32 + quad * 8];
        #pragma unroll
        for (int j = 0; j < 2; j++)
            bfr[j] = *(const short8*)&Bs[(wn + j * 16 + l16) * 520 + ks * 32 + quad * 8];
        #pragma unroll
        for (int i = 0; i < 2; i++)
            #pragma unroll
            for (int j = 0; j < 2; j++)
                acc[i][j] = __builtin_amdgcn_mfma_f32_16x16x32_bf16(af[i], bfr[j], acc[i][j], 0, 0, 0);
    }
}

// ---------- K1: prep (round-6 proven layout) ----------
// [0,128):     vis rows: fp32-norm + bf16-norm + raw bf16 (+ zero loss/corrSS in bid 0)
// [128,896):   weight cvt fp32->bf16 (wq, wv, wo)
// [896,1024):  tm rows -> normalized bf16 negsb[512:]
// [1024,1088): wk -> transposed f16 wkT[j][d]
// [1088,1152): wo -> transposed bf16 woT[c][j]
__global__ __launch_bounds__(256) void prep(const float* __restrict__ vis,
                                            const float* __restrict__ ipw,
                                            const float* __restrict__ opw,
                                            const float* __restrict__ tm,
                                            float* __restrict__ vis_n,
                                            u16* __restrict__ vis_nb,
                                            u16* __restrict__ vis_b,
                                            u16* __restrict__ wqb,
                                            u16* __restrict__ wvb,
                                            u16* __restrict__ wob,
                                            u16* __restrict__ negsb,
                                            u16* __restrict__ wkT,
                                            u16* __restrict__ woT,
                                            float* __restrict__ corrSS,
                                            float* __restrict__ loss0)
{
    int bid = blockIdx.x;
    int t = threadIdx.x;
    if (bid >= 1088) {                       // wo transpose -> bf16 woT[c][j]
        __shared__ __align__(16) u16 T[64 * 72];
        int idx = bid - 1088;
        int a = idx >> 3, cb = idx & 7;
        int r = t >> 2, c0 = (t & 3) * 16;
        #pragma unroll
        for (int q = 0; q < 4; q++) {
            float4 v = *(const float4*)&opw[(size_t)(a * 64 + r) * 512 + cb * 64 + c0 + q * 4];
            T[(c0 + q * 4 + 0) * 72 + r] = f2bf(v.x);
            T[(c0 + q * 4 + 1) * 72 + r] = f2bf(v.y);
            T[(c0 + q * 4 + 2) * 72 + r] = f2bf(v.z);
            T[(c0 + q * 4 + 3) * 72 + r] = f2bf(v.w);
        }
        __syncthreads();
        int j = t >> 2, ch = (t & 3) * 16;
        *(uint4*)&woT[(size_t)(cb * 64 + j) * 512 + a * 64 + ch]     = *(const uint4*)&T[j * 72 + ch];
        *(uint4*)&woT[(size_t)(cb * 64 + j) * 512 + a * 64 + ch + 8] = *(const uint4*)&T[j * 72 + ch + 8];
        return;
    }
    if (bid >= 1024) {                       // wk transpose -> f16
        __shared__ __align__(16) u16 T[64 * 72];
        int idx = bid - 1024;
        int a = idx >> 3, cb = idx & 7;
        const float* wk = ipw + 262144;      // rows 512..1023 of in_proj_w
        int r = t >> 2, c0 = (t & 3) * 16;
        #pragma unroll
        for (int q = 0; q < 4; q++) {
            float4 v = *(const float4*)&wk[(size_t)(a * 64 + r) * 512 + cb * 64 + c0 + q * 4];
            T[(c0 + q * 4 + 0) * 72 + r] = f2h(v.x);
            T[(c0 + q * 4 + 1) * 72 + r] = f2h(v.y);
            T[(c0 + q * 4 + 2) * 72 + r] = f2h(v.z);
            T[(c0 + q * 4 + 3) * 72 + r] = f2h(v.w);
        }
        __syncthreads();
        int j = t >> 2, ch = (t & 3) * 16;
        *(uint4*)&wkT[(size_t)(cb * 64 + j) * 512 + a * 64 + ch]     = *(const uint4*)&T[j * 72 + ch];
        *(uint4*)&wkT[(size_t)(cb * 64 + j) * 512 + a * 64 + ch + 8] = *(const uint4*)&T[j * 72 + ch + 8];
        return;
    }
    if (bid >= 896) {                        // tm rows -> normalized negsb[512:]
        int wave = t >> 6, lane = t & 63;
        int j = 512 + (bid - 896) * 4 + wave;
        const float* row = tm + (size_t)(j - 512) * 512 + lane * 8;
        float4 x0 = *(const float4*)row;
        float4 x1 = *(const float4*)(row + 4);
        float ss = x0.x*x0.x + x0.y*x0.y + x0.z*x0.z + x0.w*x0.w
                 + x1.x*x1.x + x1.y*x1.y + x1.z*x1.z + x1.w*x1.w;
        ss = wave_sum(ss);
        float inv = 1.0f / fmaxf(sqrtf(ss), EPS);
        uint4 pk;
        pk.x = pack2(x0.x*inv, x0.y*inv); pk.y = pack2(x0.z*inv, x0.w*inv);
        pk.z = pack2(x1.x*inv, x1.y*inv); pk.w = pack2(x1.z*inv, x1.w*inv);
        *(uint4*)(negsb + (size_t)j * 512 + lane * 8) = pk;
        return;
    }
    if (bid >= 128) {                        // weight conversions
        int i = ((bid - 128) * 256 + t) * 4;
        const float* src; u16* dst; int j;
        if (i < 262144)      { j = i;          src = ipw + j;          dst = wqb + j; }
        else if (i < 524288) { j = i - 262144; src = ipw + 524288 + j; dst = wvb + j; }
        else                 { j = i - 524288; src = opw + j;          dst = wob + j; }
        float4 v = *(const float4*)src;
        uint2 pk; pk.x = pack2(v.x, v.y); pk.y = pack2(v.z, v.w);
        *(uint2*)dst = pk;
        return;
    }
    if (bid == 0) {
        if (t == 0) loss0[0] = 0.0f;
        corrSS[t] = 0.0f;
        corrSS[t + 256] = 0.0f;
    }
    int wave = t >> 6, lane = t & 63;
    int b = bid * 4 + wave;                  // B = 512
    const float* row = vis + (size_t)b * 512 + lane * 8;
    float4 x0 = *(const float4*)row;
    float4 x1 = *(const float4*)(row + 4);
    uint4 rk;
    rk.x = pack2(x0.x, x0.y); rk.y = pack2(x0.z, x0.w);
    rk.z = pack2(x1.x, x1.y); rk.w = pack2(x1.z, x1.w);
    *(uint4*)(vis_b + (size_t)b * 512 + lane * 8) = rk;
    float ss = x0.x*x0.x + x0.y*x0.y + x0.z*x0.z + x0.w*x0.w
             + x1.x*x1.x + x1.y*x1.y + x1.z*x1.z + x1.w*x1.w;
    ss = wave_sum(ss);
    float inv = 1.0f / fmaxf(sqrtf(ss), EPS);
    float4 y0, y1;
    y0.x = x0.x*inv; y0.y = x0.y*inv; y0.z = x0.z*inv; y0.w = x0.w*inv;
    y1.x = x1.x*inv; y1.y = x1.y*inv; y1.z = x1.z*inv; y1.w = x1.w*inv;
    *(float4*)(vis_n + (size_t)b * 512 + lane * 8)     = y0;
    *(float4*)(vis_n + (size_t)b * 512 + lane * 8 + 4) = y1;
    uint4 pk;
    pk.x = pack2(y0.x, y0.y); pk.y = pack2(y0.z, y0.w);
    pk.z = pack2(y1.x, y1.y); pk.w = pack2(y1.z, y1.w);
    *(uint4*)(vis_nb + (size_t)b * 512 + lane * 8) = pk;
}

// ---------- K2: mid (200 blocks; qqk now 3-barrier single-phase) ----------
// [0,64):     qqk: q-proj + qk-proj (bf16/f16 staged, single-phase)
// [64,128):   ns_right: ns[:,512:1024] = vis_nb @ negsb[512:]^T (single-phase)
// [128,192):  G = vis_nb @ woT^T (single-phase, bf16 out)
// [192,200):  vb[b] = vis_n[b] . bo
__global__ __launch_bounds__(256) void mid(const u16* __restrict__ visb,
                                           const u16* __restrict__ vis_nb,
                                           const u16* __restrict__ wqb,
                                           const float* __restrict__ ipb,
                                           const u16* __restrict__ wkT,
                                           u16* __restrict__ qkb,
                                           const u16* __restrict__ negsb,
                                           float* __restrict__ ns,
                                           const u16* __restrict__ woT,
                                           u16* __restrict__ G,
                                           const float* __restrict__ opb,
                                           float* __restrict__ vb,
                                           const float* __restrict__ vis_n)
{
    __shared__ __align__(16) u16 SMEM[2 * 64 * 520];   // 133,120 B
    const int bid = blockIdx.x;
    const int t = threadIdx.x, lane = t & 63, w = t >> 6;
    const int wm = (w >> 1) * 32, wn = (w & 1) * 32;
    const int l16 = lane & 15, quad = lane >> 4;

    if (bid >= 192) {
        // ---- vb: 8 blocks x 4 waves x 16 b ----
        int idx = bid - 192;
        #pragma unroll 2
        for (int k = 0; k < 16; k++) {
            int b = idx * 64 + w * 16 + k;
            const float* vn = vis_n + (size_t)b * 512 + lane * 8;
            float4 a = *(const float4*)vn, c = *(const float4*)(vn + 4);
            const float* bo = opb + lane * 8;
            float4 b0 = *(const float4*)bo, b1 = *(const float4*)(bo + 4);
            float dt = a.x*b0.x + a.y*b0.y + a.z*b0.z + a.w*b0.w
                     + c.x*b1.x + c.y*b1.y + c.z*b1.z + c.w*b1.w;
            dt = wave_sum(dt);
            if (lane == 0) vb[b] = dt;
        }
        return;
    }

    u16* As = SMEM;              // 64x520
    u16* Bs = SMEM + 33280;      // 64x520

    if (bid >= 64) {
        // ---- ns_right (64) or G (64): single-phase K=512 ----
        bool isG = (bid >= 128);
        int idx = bid - (isG ? 128 : 64);
        int m0 = (idx & 7) * 64, n0 = (idx >> 3) * 64;
        const u16* Bsrc = isG ? (woT + (size_t)n0 * 512)
                              : (negsb + (size_t)(512 + n0) * 512);
        f32x4 acc[2][2];
        for (int i = 0; i < 2; i++)
            for (int j = 0; j < 2; j++)
                for (int e = 0; e < 4; e++) acc[i][j][e] = 0.f;
        stage64x512(vis_nb + (size_t)m0 * 512, 512, As);
        stage64x512(Bsrc, 512, Bs);
        __syncthreads();
        mfma_k512(As, Bs, acc);
        #pragma unroll
        for (int i = 0; i < 2; i++)
            #pragma unroll
            for (int j = 0; j < 2; j++)
                #pragma unroll
                for (int r = 0; r < 4; r++) {
                    int row = m0 + wm + i * 16 + quad * 4 + r;
                    int col = n0 + wn + j * 16 + l16;
                    if (isG) G[(size_t)row * 512 + col] = f2bf(acc[i][j][r]);
                    else     ns[(size_t)row * 1024 + 512 + col] = acc[i][j][r];
                }
        return;
    }

    // ---- qqk: single-phase, 3 barriers total ----
    const int m0 = (bid & 7) * 64, h = bid >> 3;

    f32x4 acc[2][2];
    for (int i = 0; i < 2; i++)
        for (int j = 0; j < 2; j++)
            for (int e = 0; e < 4; e++) acc[i][j][e] = 0.f;

    // Phase A: q = vis_b(m0 tile) @ wq_h^T, K=512 single-stage
    stage64x512(visb + (size_t)m0 * 512, 512, As);
    stage64x512(wqb + (size_t)(h * 64) * 512, 512, Bs);
    __syncthreads();                         // barrier 1
    mfma_k512(As, Bs, acc);
    __syncthreads();                         // barrier 2: all LDS reads done, safe to overwrite

    // Qf (f16, 64x72) at SMEM[0]; Bk (f16, 512x72) at SMEM[4608]
    u16* Qf = SMEM;
    u16* Bk = SMEM + 4608;
    #pragma unroll
    for (int i = 0; i < 2; i++)
        #pragma unroll
        for (int j = 0; j < 2; j++)
            #pragma unroll
            for (int r = 0; r < 4; r++) {
                int rl = wm + i * 16 + quad * 4 + r;
                int cl = wn + j * 16 + l16;
                Qf[rl * 72 + cl] = f2h(acc[i][j][r] + ipb[h * 64 + cl]);
            }
    // stage full wkT panel: rows 0..512, cols h*64..h*64+64 (f16)
    {
        int r0 = t >> 3;                     // 32 rows per pass
        int c0 = (t & 7) * 8;                // 8 f16 = 16B
        #pragma unroll
        for (int pass = 0; pass < 16; pass++) {
            int r = pass * 32 + r0;
            *(uint4*)&Bk[r * 72 + c0] = *(const uint4*)&wkT[(size_t)r * 512 + h * 64 + c0];
        }
    }
    __syncthreads();                         // barrier 3

    // Phase B: qk = Qf @ Bk^T over all 8 jt tiles, no further syncs
    for (int jt = 0; jt < 8; jt++) {
        f32x4 a2[2][2];
        for (int i = 0; i < 2; i++)
            for (int j = 0; j < 2; j++)
                for (int e = 0; e < 4; e++) a2[i][j][e] = 0.f;
        #pragma unroll
        for (int ks = 0; ks < 2; ks++) {
            half8 af[2], bfr[2];
            #pragma unroll
            for (int i = 0; i < 2; i++)
                af[i] = *(const half8*)&Qf[(wm + i * 16 + l16) * 72 + ks * 32 + quad * 8];
            #pragma unroll
            for (int j = 0; j < 2; j++)
                bfr[j] = *(const half8*)&Bk[(jt * 64 + wn + j * 16 + l16) * 72 + ks * 32 + quad * 8];
            #pragma unroll
            for (int i = 0; i < 2; i++)
                #pragma unroll
                for (int j = 0; j < 2; j++)
                    a2[i][j] = __builtin_amdgcn_mfma_f32_16x16x32_f16(af[i], bfr[j], a2[i][j], 0, 0, 0);
        }
        #pragma unroll
        for (int i = 0; i < 2; i++)
            #pragma unroll
            for (int j = 0; j < 2; j++)
                #pragma unroll
                for (int r = 0; r < 4; r++) {
                    int rb = m0 + wm + i * 16 + quad * 4 + r;
                    int cj = jt * 64 + wn + j * 16 + l16;
                    qkb[((size_t)rb * 8 + h) * 512 + cj] = f2bf(a2[i][j][r]);
                }
    }
}

// ---------- K3: attention (fused tf stream, round-6 proven schedule); 512 x 1024 ----------
__global__ __launch_bounds__(1024) void attn(const float* __restrict__ tf,
                                             const float* __restrict__ vis_n,
                                             const u16* __restrict__ qkb,
                                             u16* __restrict__ u_allb,
                                             float* __restrict__ out_cs)
{
    __shared__ __align__(16) u16 Xs[96 * 520];
    __shared__ __align__(16) u16 Qs[16 * 520];
    __shared__ __align__(16) u16 Ps[16 * 104];
    __shared__ float Sc[16 * 100];
    __shared__ float sm_[96], srt[96], linv[8];

    const int b = blockIdx.x;
    const int t = threadIdx.x, w = t >> 6, lane = t & 63;
    const int l16 = lane & 15, quad = lane >> 4;

    const float4* v4 = (const float4*)(vis_n + (size_t)b * 512 + lane * 8);
    float4 va = v4[0], vbv = v4[1];

    #pragma unroll
    for (int i = 0; i < 3; i++) {
        int m0r = w + i * 32;
        int m1r = m0r + 16;
        const float4* pa = (const float4*)(tf + ((size_t)b * 96 + m0r) * 512 + lane * 8);
        const float4* pb = (const float4*)(tf + ((size_t)b * 96 + m1r) * 512 + lane * 8);
        float4 a0 = pa[0], c0 = pa[1];
        float4 a1 = pb[0], c1 = pb[1];
        float ss0 = a0.x*a0.x + a0.y*a0.y + a0.z*a0.z + a0.w*a0.w
                  + c0.x*c0.x + c0.y*c0.y + c0.z*c0.z + c0.w*c0.w;
        float dt0 = a0.x*va.x + a0.y*va.y + a0.z*va.z + a0.w*va.w
                  + c0.x*vbv.x + c0.y*vbv.y + c0.z*vbv.z + c0.w*vbv.w;
        float ss1 = a1.x*a1.x + a1.y*a1.y + a1.z*a1.z + a1.w*a1.w
                  + c1.x*c1.x + c1.y*c1.y + c1.z*c1.z + c1.w*c1.w;
        float dt1 = a1.x*va.x + a1.y*va.y + a1.z*va.z + a1.w*va.w
                  + c1.x*vbv.x + c1.y*vbv.y + c1.z*vbv.z + c1.w*vbv.w;
        #pragma unroll
        for (int off = 32; off; off >>= 1) {
            ss0 += __shfl_xor(ss0, off, 64);
            dt0 += __shfl_xor(dt0, off, 64);
            ss1 += __shfl_xor(ss1, off, 64);
            dt1 += __shfl_xor(dt1, off, 64);
        }
        if (lane == 0) {
            sm_[m0r] = dt0 / fmaxf(sqrtf(ss0), EPS);
            sm_[m1r] = dt1 / fmaxf(sqrtf(ss1), EPS);
        }
        uint4 pk0, pk1;
        pk0.x = pack2(a0.x, a0.y); pk0.y = pack2(a0.z, a0.w);
        pk0.z = pack2(c0.x, c0.y); pk0.w = pack2(c0.z, c0.w);
        pk1.x = pack2(a1.x, a1.y); pk1.y = pack2(a1.z, a1.w);
        pk1.z = pack2(c1.x, c1.y); pk1.w = pack2(c1.z, c1.w);
        *(uint4*)&Xs[m0r * 520 + lane * 8] = pk0;
        *(uint4*)&Xs[m1r * 520 + lane * 8] = pk1;
    }
    if (w < 8) {
        *(uint4*)&Qs[w * 520 + lane * 8] = *(const uint4*)(qkb + ((size_t)b * 8 + w) * 512 + lane * 8);
    } else {
        uint4 z; z.x = 0; z.y = 0; z.z = 0; z.w = 0;
        *(uint4*)&Qs[w * 520 + lane * 8] = z;
    }
    __syncthreads();

    if (w < 6) {
        f32x4 acc;
        for (int e = 0; e < 4; e++) acc[e] = 0.f;
        #pragma unroll
        for (int ks = 0; ks < 16; ks++) {
            short8 a = *(const short8*)&Xs[(w * 16 + l16) * 520 + ks * 32 + quad * 8];
            short8 q = *(const short8*)&Qs[l16 * 520 + ks * 32 + quad * 8];
            acc = __builtin_amdgcn_mfma_f32_16x16x32_bf16(a, q, acc, 0, 0, 0);
        }
        #pragma unroll
        for (int r = 0; r < 4; r++)
            Sc[l16 * 100 + w * 16 + quad * 4 + r] = acc[r] * 0.125f;
    }
    __syncthreads();

    if (w < 8) {
        float e0 = __expf(Sc[w * 100 + lane]);
        float e1 = (lane < 32) ? __expf(Sc[w * 100 + 64 + lane]) : 0.f;
        float l = wave_sum(e0 + e1);
        Ps[w * 104 + lane] = f2bf(e0);
        if (lane < 32) Ps[w * 104 + 64 + lane] = f2bf(e1);
        if (lane == 0) linv[w] = 1.0f / l;
    } else {
        Ps[w * 104 + lane] = 0;
        if (lane < 40) Ps[w * 104 + 64 + lane] = 0;
    }
    if (t < 96) {
        float v = sm_[t]; int r = 0;
        for (int j = 0; j < 96; j++) {
            float u = sm_[j];
            r += (u > v) || (u == v && j < t);
        }
        srt[r] = v;
    }
    __syncthreads();

    #pragma unroll
    for (int jj = 0; jj < 2; jj++) {
        int n0 = (w * 2 + jj) * 16;
        f32x4 acc;
        for (int e = 0; e < 4; e++) acc[e] = 0.f;
        #pragma unroll
        for (int ks = 0; ks < 3; ks++) {
            short8 ap = *(const short8*)&Ps[l16 * 104 + ks * 32 + quad * 8];
            short8 bx;
            #pragma unroll
            for (int j = 0; j < 8; j++)
                bx[j] = (short)Xs[(ks * 32 + quad * 8 + j) * 520 + n0 + l16];
            acc = __builtin_amdgcn_mfma_f32_16x16x32_bf16(ap, bx, acc, 0, 0, 0);
        }
        if (quad < 2) {
            #pragma unroll
            for (int r = 0; r < 4; r++) {
                int h = quad * 4 + r;
                u_allb[((size_t)b * 8 + h) * 512 + n0 + l16] = f2bf(acc[r] * linv[h]);
            }
        }
    }
    if (t < 3) {
        float mean = 0.f;
        #pragma unroll 8
        for (int i = 0; i < 32; i++) mean += srt[t * 32 + i];
        mean *= (1.0f / 32.0f);
        float var = 0.f;
        #pragma unroll 8
        for (int i = 0; i < 32; i++) { float d = srt[t * 32 + i] - mean; var += d * d; }
        var *= (1.0f / 31.0f);
        out_cs[b * 3 + t] = mean / (sqrtf(var) + 1e-6f);
    }
}

// ---------- K4: ghead: ctx_h = u_h @ Wv_h^T + bv_h (single-phase K=512), bf16 out ----------
__global__ __launch_bounds__(256) void ghead(const u16* __restrict__ u_allb,
                                             const u16* __restrict__ wvb,
                                             const float* __restrict__ bv,
                                             u16* __restrict__ ctxb)
{
    __shared__ __align__(16) u16 As[64 * 520];
    __shared__ __align__(16) u16 Bs[64 * 520];
    const int bid = blockIdx.x;
    const int m0 = (bid & 7) * 64, h = bid >> 3;
    const int t = threadIdx.x, lane = t & 63, w = t >> 6;
    const int wm = (w >> 1) * 32, wn = (w & 1) * 32;
    const int l16 = lane & 15, quad = lane >> 4;

    f32x4 acc[2][2];
    for (int i = 0; i < 2; i++)
        for (int j = 0; j < 2; j++)
            for (int e = 0; e < 4; e++) acc[i][j][e] = 0.f;

    stage64x512(u_allb + (size_t)m0 * 4096 + (size_t)h * 512, 4096, As);
    stage64x512(wvb + (size_t)h * 64 * 512, 512, Bs);
    __syncthreads();
    mfma_k512(As, Bs, acc);

    for (int i = 0; i < 2; i++) {
        int row = m0 + wm + i * 16 + quad * 4;
        for (int j = 0; j < 2; j++) {
            int col = wn + j * 16 + l16;
            float bb = bv[h * 64 + col];
            for (int r = 0; r < 4; r++)
                ctxb[(size_t)(row + r) * 512 + h * 64 + col] = f2bf(acc[i][j][r] + bb);
        }
    }
}

// ---------- K5: tail2 (128 blocks, both halves need only ctxb) ----------
// [0,64):   gcorr: corrected = ctx @ Wo^T + bo (fp32 out + row sumsq)
// [64,128): nsG:   ns[:,0:512] = G @ ctx^T + vb
__global__ __launch_bounds__(256) void tail2(const u16* __restrict__ ctxb,
                                             const u16* __restrict__ wob,
                                             const float* __restrict__ bias,
                                             float* __restrict__ Cf,
                                             float* __restrict__ corrSS,
                                             const u16* __restrict__ G,
                                             const float* __restrict__ vb,
                                             float* __restrict__ ns)
{
    __shared__ __align__(16) u16 As[64 * 520];
    __shared__ __align__(16) u16 Bs[64 * 520];
    const int bid = blockIdx.x;
    const int t = threadIdx.x, lane = t & 63, w = t >> 6;
    const int wm = (w >> 1) * 32, wn = (w & 1) * 32;
    const int l16 = lane & 15, quad = lane >> 4;

    f32x4 acc[2][2];
    for (int i = 0; i < 2; i++)
        for (int j = 0; j < 2; j++)
            for (int e = 0; e < 4; e++) acc[i][j][e] = 0.f;

    if (bid < 64) {
        // ---- gcorr ----
        const int m0 = (bid & 7) * 64, n0 = (bid >> 3) * 64;
        stage64x512(ctxb + (size_t)m0 * 512, 512, As);
        stage64x512(wob + (size_t)n0 * 512, 512, Bs);
        __syncthreads();
        mfma_k512(As, Bs, acc);
        #pragma unroll
        for (int i = 0; i < 2; i++) {
            #pragma unroll
            for (int r = 0; r < 4; r++) {
                int row = m0 + wm + i * 16 + quad * 4 + r;
                float s = 0.f;
                #pragma unroll
                for (int j = 0; j < 2; j++) {
                    int col = n0 + wn + j * 16 + l16;
                    float v = acc[i][j][r] + bias[col];
                    Cf[(size_t)row * 512 + col] = v;
                    s += v * v;
                }
                s += __shfl_xor(s, 1, 64); s += __shfl_xor(s, 2, 64);
                s += __shfl_xor(s, 4, 64); s += __shfl_xor(s, 8, 64);
                if (l16 == 0) atomicAdd(&corrSS[row], s);
            }
        }
        return;
    }

    // ---- nsG: ns[m][n] = G[m] . ctx[n] + vb[m] ----
    const int idx = bid - 64;
    const int m0 = (idx & 7) * 64, n0 = (idx >> 3) * 64;
    stage64x512(G + (size_t)m0 * 512, 512, As);
    stage64x512(ctxb + (size_t)n0 * 512, 512, Bs);
    __syncthreads();
    mfma_k512(As, Bs, acc);
    for (int i = 0; i < 2; i++) {
        int row = m0 + wm + i * 16 + quad * 4;
        for (int j = 0; j < 2; j++) {
            int col = n0 + wn + j * 16 + l16;
            for (int r = 0; r < 4; r++)
                ns[(size_t)(row + r) * 1024 + col] = acc[i][j][r] + vb[row + r];
        }
    }
}

// ---------- K6: top-5 + loss; per-wave top-5 (no sync) then single merge ----------
__global__ __launch_bounds__(256) void topk_loss(const float* __restrict__ ns,
                                                 const float* __restrict__ corrSS,
                                                 const float* __restrict__ tau_p_log,
                                                 const float* __restrict__ tau_n_log,
                                                 float* __restrict__ out_loss)
{
    __shared__ float invn[512];
    __shared__ float cv[20];
    __shared__ int   cjx[20];
    int b = blockIdx.x, t = threadIdx.x;
    int w = t >> 6, lane = t & 63;

    {
        float s0 = corrSS[t], s1 = corrSS[t + 256];
        invn[t]       = 1.0f / fmaxf(sqrtf(s0), EPS);
        invn[t + 256] = 1.0f / fmaxf(sqrtf(s1), EPS);
    }
    __syncthreads();

    const float4 raw = *(const float4*)(ns + (size_t)b * 1024 + t * 4);
    float lv[4] = {raw.x, raw.y, raw.z, raw.w};
    int   li[4] = {t * 4, t * 4 + 1, t * 4 + 2, t * 4 + 3};
    if (t < 128) {
        lv[0] *= invn[t * 4];     lv[1] *= invn[t * 4 + 1];
        lv[2] *= invn[t * 4 + 2]; lv[3] *= invn[t * 4 + 3];
    }
    #pragma unroll
    for (int i = 1; i < 4; i++) {
        float kv = lv[i]; int kx = li[i];
        int j = i - 1;
        #pragma unroll
        for (int k = 0; k < 3; k++) {
            if (j >= 0 && lv[j] < kv) { lv[j + 1] = lv[j]; li[j + 1] = li[j]; j--; }
        }
        lv[j + 1] = kv; li[j + 1] = kx;
    }
    int lp = 0;
    #pragma unroll
    for (int rd = 0; rd < 5; rd++) {
        float mv = (lp < 4) ? lv[lp] : -1e30f;
        int   mi = (lp < 4) ? li[lp] : 0;
        int   ml = lane;
        #pragma unroll
        for (int off = 32; off; off >>= 1) {
            float ov = __shfl_xor(mv, off, 64);
            int   oi = __shfl_xor(mi, off, 64);
            int   ol = __shfl_xor(ml, off, 64);
            if (ov > mv || (ov == mv && ol < ml)) { mv = ov; mi = oi; ml = ol; }
        }
        if (lane == ml) lp++;
        if (lane == 0) { cv[w * 5 + rd] = mv; cjx[w * 5 + rd] = mi; }
    }
    __syncthreads();
    if (w == 0) {
        float v  = (lane < 20) ? cv[lane] : -1e30f;
        int   jx = (lane < 20) ? cjx[lane] : 0;
        float tn = expf(tau_n_log[0]);
        float itn = 1.0f / tn;
        float nsum = 0.f; int coll = 0;
        #pragma unroll
        for (int rd = 0; rd < 5; rd++) {
            float mv = v; int ml = lane; int mj = jx;
            #pragma unroll
            for (int off = 32; off; off >>= 1) {
                float ov = __shfl_xor(mv, off, 64);
                int   oj = __shfl_xor(mj, off, 64);
                int   ol = __shfl_xor(ml, off, 64);
                if (ov > mv || (ov == mv && ol < ml)) { mv = ov; mj = oj; ml = ol; }
            }
            int mult = (mj < 512) ? 2 : 1;
            int take = 5 - coll;
            take = (mult < take) ? mult : take;
            if (take < 0) take = 0;
            nsum += (float)take * __expf(mv * itn);
            coll += take;
            if (lane == ml) v = -1e30f;
        }
        if (lane == 0) {
            float pos = ns[(size_t)b * 1024 + b] * invn[b];   // cos(vis_n, corr_n)
            float tp = expf(tau_p_log[0]);
            float p = expf(pos / tp);
            float term = logf(p / (p + nsum + 1e-8f));
            atomicAdd(out_loss, -term * (1.0f / 512.0f));
        }
    }
}

// ---------- launch ----------
extern "C" void kernel_launch(void* const* d_in, const int* in_sizes, int n_in,
                              void* d_out, int out_size, void* d_ws, size_t ws_size,
                              hipStream_t stream) {
    const float* vis = (const float*)d_in[0];
    const float* tf  = (const float*)d_in[1];
    const float* ipw = (const float*)d_in[2];
    const float* ipb = (const float*)d_in[3];
    const float* opw = (const float*)d_in[4];
    const float* opb = (const float*)d_in[5];
    const float* tm  = (const float*)d_in[6];
    const float* tpl = (const float*)d_in[7];
    const float* tnl = (const float*)d_in[8];

    float* out       = (float*)d_out;
    float* out_loss  = out;
    float* out_corr  = out + 1;                  // (512,512)
    float* out_cs    = out + 1 + 512 * 512;      // (512,3)

    char* p = (char*)d_ws;
    auto alloc = [&](size_t bytes) { char* r = p; p += (bytes + 255) & ~(size_t)255; return r; };
    float* vis_n  = (float*)alloc(512 * 512 * 4);
    u16*   vis_nb = (u16*)  alloc(512 * 512 * 2);
    u16*   vis_b  = (u16*)  alloc(512 * 512 * 2);
    u16*   wqb    = (u16*)  alloc(512 * 512 * 2);
    u16*   wvb    = (u16*)  alloc(512 * 512 * 2);
    u16*   wob    = (u16*)  alloc(512 * 512 * 2);
    u16*   wkT    = (u16*)  alloc(512 * 512 * 2);
    u16*   woT    = (u16*)  alloc(512 * 512 * 2);
    u16*   G      = (u16*)  alloc(512 * 512 * 2);
    u16*   qkb    = (u16*)  alloc((size_t)512 * 8 * 512 * 2);
    u16*   u_allb = (u16*)  alloc((size_t)512 * 8 * 512 * 2);
    u16*   ctxb   = (u16*)  alloc(512 * 512 * 2);
    u16*   negsb  = (u16*)  alloc(1024 * 512 * 2);
    float* ns     = (float*)alloc(512 * 1024 * 4);
    float* corrSS = (float*)alloc(512 * 4);
    float* vb     = (float*)alloc(512 * 4);

    const float* bv = ipb + 2 * 512;

    prep<<<1152, 256, 0, stream>>>(vis, ipw, opw, tm, vis_n, vis_nb, vis_b,
                                   wqb, wvb, wob, negsb, wkT, woT, corrSS, out_loss);
    mid<<<200, 256, 0, stream>>>(vis_b, vis_nb, wqb, ipb, wkT, qkb, negsb, ns,
                                 woT, G, opb, vb, vis_n);
    attn<<<512, 1024, 0, stream>>>(tf, vis_n, qkb, u_allb, out_cs);
    ghead<<<64, 256, 0, stream>>>(u_allb, wvb, bv, ctxb);
    tail2<<<128, 256, 0, stream>>>(ctxb, wob, opb, out_corr, corrSS, G, vb, ns);
    topk_loss<<<512, 256, 0, stream>>>(ns, corrSS, tpl, tnl, out_loss);
}

// Round 12
// 218.688 us; speedup vs baseline: 1.0909x; 1.0064x over previous
//
#include <hip/hip_runtime.h>
#include <math.h>

typedef unsigned short u16;
typedef unsigned int u32;
typedef __attribute__((ext_vector_type(8))) short short8;      // 8 bf16 (4 VGPRs) MFMA A/B frag
typedef __attribute__((ext_vector_type(8))) _Float16 half8;    // 8 f16 MFMA A/B frag
typedef __attribute__((ext_vector_type(4))) float f32x4;       // MFMA C/D frag

#define EPS 1e-8f

// ---------- helpers ----------
__device__ inline float bf2f(u16 u) {
    union { u32 i; float f; } v; v.i = ((u32)u) << 16; return v.f;
}
__device__ inline u16 f2bf(float f) {  // RNE (software — v_cvt_pk_bf16_f32 is NOT RNE-equivalent, round-10 failure)
    union { float f; u32 u; } v; v.f = f;
    u32 r = v.u + 0x7fffu + ((v.u >> 16) & 1u);
    return (u16)(r >> 16);
}
__device__ inline u16 f2h(float f) {   // f32 -> f16 RNE
    _Float16 h = (_Float16)f;
    union { _Float16 hh; u16 u; } v; v.hh = h; return v.u;
}
__device__ inline u32 pack2(float a, float b) {
    return (u32)f2bf(a) | ((u32)f2bf(b) << 16);
}
__device__ inline float wave_sum(float v) {
    for (int off = 32; off; off >>= 1) v += __shfl_xor(v, off, 64);
    return v;
}

// ---- single-phase 64x64 tile, K=512: stage whole 64x512 into LDS (stride 520) ----
__device__ __forceinline__ void stage64x512(const u16* __restrict__ Ag, size_t lda,
                                            u16* __restrict__ As) {
    const int t = threadIdx.x;
    const int srow = t >> 2;
    const int c0 = (t & 3) * 8;
    #pragma unroll
    for (int kk = 0; kk < 16; kk++) {
        int c = c0 + kk * 32;
        *(uint4*)&As[srow * 520 + c] = *(const uint4*)&Ag[(size_t)srow * lda + c];
    }
}
__device__ __forceinline__ void mfma_k512(const u16* __restrict__ As,
                                          const u16* __restrict__ Bs,
                                          f32x4 (&acc)[2][2]) {
    const int t = threadIdx.x, lane = t & 63, w = t >> 6;
    const int wm = (w >> 1) * 32, wn = (w & 1) * 32;
    const int l16 = lane & 15, quad = lane >> 4;
    #pragma unroll
    for (int ks = 0; ks < 16; ks++) {
        short8 af[2], bfr[2];
        #pragma unroll
        for (int i = 0; i < 2; i++)
            af[i] = *(const short8*)&As[(wm + i * 16 + l16) * 520 + ks * 32 + quad * 8];
        #pragma unroll
        for (int j = 0; j < 2; j++)
            bfr[j] = *(const short8*)&Bs[(wn + j * 16 + l16) * 520 + ks * 32 + quad * 8];
        #pragma unroll
        for (int i = 0; i < 2; i++)
            #pragma unroll
            for (int j = 0; j < 2; j++)
                acc[i][j] = __builtin_amdgcn_mfma_f32_16x16x32_bf16(af[i], bfr[j], acc[i][j], 0, 0, 0);
    }
}

// ---------- K1: prep (round-6 proven layout) ----------
// [0,128):     vis rows: fp32-norm + bf16-norm + raw bf16 (+ zero loss/corrSS in bid 0)
// [128,896):   weight cvt fp32->bf16 (wq, wv, wo)
// [896,1024):  tm rows -> normalized bf16 negsb[512:]
// [1024,1088): wk -> transposed f16 wkT[j][d]
// [1088,1152): wo -> transposed bf16 woT[c][j]
__global__ __launch_bounds__(256) void prep(const float* __restrict__ vis,
                                            const float* __restrict__ ipw,
                                            const float* __restrict__ opw,
                                            const float* __restrict__ tm,
                                            float* __restrict__ vis_n,
                                            u16* __restrict__ vis_nb,
                                            u16* __restrict__ vis_b,
                                            u16* __restrict__ wqb,
                                            u16* __restrict__ wvb,
                                            u16* __restrict__ wob,
                                            u16* __restrict__ negsb,
                                            u16* __restrict__ wkT,
                                            u16* __restrict__ woT,
                                            float* __restrict__ corrSS,
                                            float* __restrict__ loss0)
{
    int bid = blockIdx.x;
    int t = threadIdx.x;
    if (bid >= 1088) {                       // wo transpose -> bf16 woT[c][j]
        __shared__ __align__(16) u16 T[64 * 72];
        int idx = bid - 1088;
        int a = idx >> 3, cb = idx & 7;
        int r = t >> 2, c0 = (t & 3) * 16;
        #pragma unroll
        for (int q = 0; q < 4; q++) {
            float4 v = *(const float4*)&opw[(size_t)(a * 64 + r) * 512 + cb * 64 + c0 + q * 4];
            T[(c0 + q * 4 + 0) * 72 + r] = f2bf(v.x);
            T[(c0 + q * 4 + 1) * 72 + r] = f2bf(v.y);
            T[(c0 + q * 4 + 2) * 72 + r] = f2bf(v.z);
            T[(c0 + q * 4 + 3) * 72 + r] = f2bf(v.w);
        }
        __syncthreads();
        int j = t >> 2, ch = (t & 3) * 16;
        *(uint4*)&woT[(size_t)(cb * 64 + j) * 512 + a * 64 + ch]     = *(const uint4*)&T[j * 72 + ch];
        *(uint4*)&woT[(size_t)(cb * 64 + j) * 512 + a * 64 + ch + 8] = *(const uint4*)&T[j * 72 + ch + 8];
        return;
    }
    if (bid >= 1024) {                       // wk transpose -> f16
        __shared__ __align__(16) u16 T[64 * 72];
        int idx = bid - 1024;
        int a = idx >> 3, cb = idx & 7;
        const float* wk = ipw + 262144;      // rows 512..1023 of in_proj_w
        int r = t >> 2, c0 = (t & 3) * 16;
        #pragma unroll
        for (int q = 0; q < 4; q++) {
            float4 v = *(const float4*)&wk[(size_t)(a * 64 + r) * 512 + cb * 64 + c0 + q * 4];
            T[(c0 + q * 4 + 0) * 72 + r] = f2h(v.x);
            T[(c0 + q * 4 + 1) * 72 + r] = f2h(v.y);
            T[(c0 + q * 4 + 2) * 72 + r] = f2h(v.z);
            T[(c0 + q * 4 + 3) * 72 + r] = f2h(v.w);
        }
        __syncthreads();
        int j = t >> 2, ch = (t & 3) * 16;
        *(uint4*)&wkT[(size_t)(cb * 64 + j) * 512 + a * 64 + ch]     = *(const uint4*)&T[j * 72 + ch];
        *(uint4*)&wkT[(size_t)(cb * 64 + j) * 512 + a * 64 + ch + 8] = *(const uint4*)&T[j * 72 + ch + 8];
        return;
    }
    if (bid >= 896) {                        // tm rows -> normalized negsb[512:]
        int wave = t >> 6, lane = t & 63;
        int j = 512 + (bid - 896) * 4 + wave;
        const float* row = tm + (size_t)(j - 512) * 512 + lane * 8;
        float4 x0 = *(const float4*)row;
        float4 x1 = *(const float4*)(row + 4);
        float ss = x0.x*x0.x + x0.y*x0.y + x0.z*x0.z + x0.w*x0.w
                 + x1.x*x1.x + x1.y*x1.y + x1.z*x1.z + x1.w*x1.w;
        ss = wave_sum(ss);
        float inv = 1.0f / fmaxf(sqrtf(ss), EPS);
        uint4 pk;
        pk.x = pack2(x0.x*inv, x0.y*inv); pk.y = pack2(x0.z*inv, x0.w*inv);
        pk.z = pack2(x1.x*inv, x1.y*inv); pk.w = pack2(x1.z*inv, x1.w*inv);
        *(uint4*)(negsb + (size_t)j * 512 + lane * 8) = pk;
        return;
    }
    if (bid >= 128) {                        // weight conversions
        int i = ((bid - 128) * 256 + t) * 4;
        const float* src; u16* dst; int j;
        if (i < 262144)      { j = i;          src = ipw + j;          dst = wqb + j; }
        else if (i < 524288) { j = i - 262144; src = ipw + 524288 + j; dst = wvb + j; }
        else                 { j = i - 524288; src = opw + j;          dst = wob + j; }
        float4 v = *(const float4*)src;
        uint2 pk; pk.x = pack2(v.x, v.y); pk.y = pack2(v.z, v.w);
        *(uint2*)dst = pk;
        return;
    }
    if (bid == 0) {
        if (t == 0) loss0[0] = 0.0f;
        corrSS[t] = 0.0f;
        corrSS[t + 256] = 0.0f;
    }
    int wave = t >> 6, lane = t & 63;
    int b = bid * 4 + wave;                  // B = 512
    const float* row = vis + (size_t)b * 512 + lane * 8;
    float4 x0 = *(const float4*)row;
    float4 x1 = *(const float4*)(row + 4);
    uint4 rk;
    rk.x = pack2(x0.x, x0.y); rk.y = pack2(x0.z, x0.w);
    rk.z = pack2(x1.x, x1.y); rk.w = pack2(x1.z, x1.w);
    *(uint4*)(vis_b + (size_t)b * 512 + lane * 8) = rk;
    float ss = x0.x*x0.x + x0.y*x0.y + x0.z*x0.z + x0.w*x0.w
             + x1.x*x1.x + x1.y*x1.y + x1.z*x1.z + x1.w*x1.w;
    ss = wave_sum(ss);
    float inv = 1.0f / fmaxf(sqrtf(ss), EPS);
    float4 y0, y1;
    y0.x = x0.x*inv; y0.y = x0.y*inv; y0.z = x0.z*inv; y0.w = x0.w*inv;
    y1.x = x1.x*inv; y1.y = x1.y*inv; y1.z = x1.z*inv; y1.w = x1.w*inv;
    *(float4*)(vis_n + (size_t)b * 512 + lane * 8)     = y0;
    *(float4*)(vis_n + (size_t)b * 512 + lane * 8 + 4) = y1;
    uint4 pk;
    pk.x = pack2(y0.x, y0.y); pk.y = pack2(y0.z, y0.w);
    pk.z = pack2(y1.x, y1.y); pk.w = pack2(y1.z, y1.w);
    *(uint4*)(vis_nb + (size_t)b * 512 + lane * 8) = pk;
}

// ---------- K2: mid (200 blocks; qqk 3-barrier single-phase) ----------
// [0,64):     qqk: q-proj + qk-proj (bf16/f16 staged, single-phase)
// [64,128):   ns_right: ns[:,512:1024] = vis_nb @ negsb[512:]^T (single-phase)
// [128,192):  G = vis_nb @ woT^T (single-phase, bf16 out)
// [192,200):  vb[b] = vis_n[b] . bo
__global__ __launch_bounds__(256) void mid(const u16* __restrict__ visb,
                                           const u16* __restrict__ vis_nb,
                                           const u16* __restrict__ wqb,
                                           const float* __restrict__ ipb,
                                           const u16* __restrict__ wkT,
                                           u16* __restrict__ qkb,
                                           const u16* __restrict__ negsb,
                                           float* __restrict__ ns,
                                           const u16* __restrict__ woT,
                                           u16* __restrict__ G,
                                           const float* __restrict__ opb,
                                           float* __restrict__ vb,
                                           const float* __restrict__ vis_n)
{
    __shared__ __align__(16) u16 SMEM[2 * 64 * 520];   // 133,120 B
    const int bid = blockIdx.x;
    const int t = threadIdx.x, lane = t & 63, w = t >> 6;
    const int wm = (w >> 1) * 32, wn = (w & 1) * 32;
    const int l16 = lane & 15, quad = lane >> 4;

    if (bid >= 192) {
        // ---- vb: 8 blocks x 4 waves x 16 b ----
        int idx = bid - 192;
        #pragma unroll 2
        for (int k = 0; k < 16; k++) {
            int b = idx * 64 + w * 16 + k;
            const float* vn = vis_n + (size_t)b * 512 + lane * 8;
            float4 a = *(const float4*)vn, c = *(const float4*)(vn + 4);
            const float* bo = opb + lane * 8;
            float4 b0 = *(const float4*)bo, b1 = *(const float4*)(bo + 4);
            float dt = a.x*b0.x + a.y*b0.y + a.z*b0.z + a.w*b0.w
                     + c.x*b1.x + c.y*b1.y + c.z*b1.z + c.w*b1.w;
            dt = wave_sum(dt);
            if (lane == 0) vb[b] = dt;
        }
        return;
    }

    u16* As = SMEM;              // 64x520
    u16* Bs = SMEM + 33280;      // 64x520

    if (bid >= 64) {
        // ---- ns_right (64) or G (64): single-phase K=512 ----
        bool isG = (bid >= 128);
        int idx = bid - (isG ? 128 : 64);
        int m0 = (idx & 7) * 64, n0 = (idx >> 3) * 64;
        const u16* Bsrc = isG ? (woT + (size_t)n0 * 512)
                              : (negsb + (size_t)(512 + n0) * 512);
        f32x4 acc[2][2];
        for (int i = 0; i < 2; i++)
            for (int j = 0; j < 2; j++)
                for (int e = 0; e < 4; e++) acc[i][j][e] = 0.f;
        stage64x512(vis_nb + (size_t)m0 * 512, 512, As);
        stage64x512(Bsrc, 512, Bs);
        __syncthreads();
        mfma_k512(As, Bs, acc);
        #pragma unroll
        for (int i = 0; i < 2; i++)
            #pragma unroll
            for (int j = 0; j < 2; j++)
                #pragma unroll
                for (int r = 0; r < 4; r++) {
                    int row = m0 + wm + i * 16 + quad * 4 + r;
                    int col = n0 + wn + j * 16 + l16;
                    if (isG) G[(size_t)row * 512 + col] = f2bf(acc[i][j][r]);
                    else     ns[(size_t)row * 1024 + 512 + col] = acc[i][j][r];
                }
        return;
    }

    // ---- qqk: single-phase, 3 barriers total ----
    const int m0 = (bid & 7) * 64, h = bid >> 3;

    f32x4 acc[2][2];
    for (int i = 0; i < 2; i++)
        for (int j = 0; j < 2; j++)
            for (int e = 0; e < 4; e++) acc[i][j][e] = 0.f;

    // Phase A: q = vis_b(m0 tile) @ wq_h^T, K=512 single-stage
    stage64x512(visb + (size_t)m0 * 512, 512, As);
    stage64x512(wqb + (size_t)(h * 64) * 512, 512, Bs);
    __syncthreads();                         // barrier 1
    mfma_k512(As, Bs, acc);
    __syncthreads();                         // barrier 2: all LDS reads done, safe to overwrite

    // Qf (f16, 64x72) at SMEM[0]; Bk (f16, 512x72) at SMEM[4608]
    u16* Qf = SMEM;
    u16* Bk = SMEM + 4608;
    #pragma unroll
    for (int i = 0; i < 2; i++)
        #pragma unroll
        for (int j = 0; j < 2; j++)
            #pragma unroll
            for (int r = 0; r < 4; r++) {
                int rl = wm + i * 16 + quad * 4 + r;
                int cl = wn + j * 16 + l16;
                Qf[rl * 72 + cl] = f2h(acc[i][j][r] + ipb[h * 64 + cl]);
            }
    // stage full wkT panel: rows 0..512, cols h*64..h*64+64 (f16)
    {
        int r0 = t >> 3;                     // 32 rows per pass
        int c0 = (t & 7) * 8;                // 8 f16 = 16B
        #pragma unroll
        for (int pass = 0; pass < 16; pass++) {
            int r = pass * 32 + r0;
            *(uint4*)&Bk[r * 72 + c0] = *(const uint4*)&wkT[(size_t)r * 512 + h * 64 + c0];
        }
    }
    __syncthreads();                         // barrier 3

    // Phase B: qk = Qf @ Bk^T over all 8 jt tiles, no further syncs
    for (int jt = 0; jt < 8; jt++) {
        f32x4 a2[2][2];
        for (int i = 0; i < 2; i++)
            for (int j = 0; j < 2; j++)
                for (int e = 0; e < 4; e++) a2[i][j][e] = 0.f;
        #pragma unroll
        for (int ks = 0; ks < 2; ks++) {
            half8 af[2], bfr[2];
            #pragma unroll
            for (int i = 0; i < 2; i++)
                af[i] = *(const half8*)&Qf[(wm + i * 16 + l16) * 72 + ks * 32 + quad * 8];
            #pragma unroll
            for (int j = 0; j < 2; j++)
                bfr[j] = *(const half8*)&Bk[(jt * 64 + wn + j * 16 + l16) * 72 + ks * 32 + quad * 8];
            #pragma unroll
            for (int i = 0; i < 2; i++)
                #pragma unroll
                for (int j = 0; j < 2; j++)
                    a2[i][j] = __builtin_amdgcn_mfma_f32_16x16x32_f16(af[i], bfr[j], a2[i][j], 0, 0, 0);
        }
        #pragma unroll
        for (int i = 0; i < 2; i++)
            #pragma unroll
            for (int j = 0; j < 2; j++)
                #pragma unroll
                for (int r = 0; r < 4; r++) {
                    int rb = m0 + wm + i * 16 + quad * 4 + r;
                    int cj = jt * 64 + wn + j * 16 + l16;
                    qkb[((size_t)rb * 8 + h) * 512 + cj] = f2bf(a2[i][j][r]);
                }
    }
}

// ---------- K3: attention (fused tf stream, round-6 proven schedule); 512 x 1024 ----------
__global__ __launch_bounds__(1024) void attn(const float* __restrict__ tf,
                                             const float* __restrict__ vis_n,
                                             const u16* __restrict__ qkb,
                                             u16* __restrict__ u_allb,
                                             float* __restrict__ out_cs)
{
    __shared__ __align__(16) u16 Xs[96 * 520];
    __shared__ __align__(16) u16 Qs[16 * 520];
    __shared__ __align__(16) u16 Ps[16 * 104];
    __shared__ float Sc[16 * 100];
    __shared__ float sm_[96], srt[96], linv[8];

    const int b = blockIdx.x;
    const int t = threadIdx.x, w = t >> 6, lane = t & 63;
    const int l16 = lane & 15, quad = lane >> 4;

    const float4* v4 = (const float4*)(vis_n + (size_t)b * 512 + lane * 8);
    float4 va = v4[0], vbv = v4[1];

    #pragma unroll
    for (int i = 0; i < 3; i++) {
        int m0r = w + i * 32;
        int m1r = m0r + 16;
        const float4* pa = (const float4*)(tf + ((size_t)b * 96 + m0r) * 512 + lane * 8);
        const float4* pb = (const float4*)(tf + ((size_t)b * 96 + m1r) * 512 + lane * 8);
        float4 a0 = pa[0], c0 = pa[1];
        float4 a1 = pb[0], c1 = pb[1];
        float ss0 = a0.x*a0.x + a0.y*a0.y + a0.z*a0.z + a0.w*a0.w
                  + c0.x*c0.x + c0.y*c0.y + c0.z*c0.z + c0.w*c0.w;
        float dt0 = a0.x*va.x + a0.y*va.y + a0.z*va.z + a0.w*va.w
                  + c0.x*vbv.x + c0.y*vbv.y + c0.z*vbv.z + c0.w*vbv.w;
        float ss1 = a1.x*a1.x + a1.y*a1.y + a1.z*a1.z + a1.w*a1.w
                  + c1.x*c1.x + c1.y*c1.y + c1.z*c1.z + c1.w*c1.w;
        float dt1 = a1.x*va.x + a1.y*va.y + a1.z*va.z + a1.w*va.w
                  + c1.x*vbv.x + c1.y*vbv.y + c1.z*vbv.z + c1.w*vbv.w;
        #pragma unroll
        for (int off = 32; off; off >>= 1) {
            ss0 += __shfl_xor(ss0, off, 64);
            dt0 += __shfl_xor(dt0, off, 64);
            ss1 += __shfl_xor(ss1, off, 64);
            dt1 += __shfl_xor(dt1, off, 64);
        }
        if (lane == 0) {
            sm_[m0r] = dt0 / fmaxf(sqrtf(ss0), EPS);
            sm_[m1r] = dt1 / fmaxf(sqrtf(ss1), EPS);
        }
        uint4 pk0, pk1;
        pk0.x = pack2(a0.x, a0.y); pk0.y = pack2(a0.z, a0.w);
        pk0.z = pack2(c0.x, c0.y); pk0.w = pack2(c0.z, c0.w);
        pk1.x = pack2(a1.x, a1.y); pk1.y = pack2(a1.z, a1.w);
        pk1.z = pack2(c1.x, c1.y); pk1.w = pack2(c1.z, c1.w);
        *(uint4*)&Xs[m0r * 520 + lane * 8] = pk0;
        *(uint4*)&Xs[m1r * 520 + lane * 8] = pk1;
    }
    if (w < 8) {
        *(uint4*)&Qs[w * 520 + lane * 8] = *(const uint4*)(qkb + ((size_t)b * 8 + w) * 512 + lane * 8);
    } else {
        uint4 z; z.x = 0; z.y = 0; z.z = 0; z.w = 0;
        *(uint4*)&Qs[w * 520 + lane * 8] = z;
    }
    __syncthreads();

    if (w < 6) {
        f32x4 acc;
        for (int e = 0; e < 4; e++) acc[e] = 0.f;
        #pragma unroll
        for (int ks = 0; ks < 16; ks++) {
            short8 a = *(const short8*)&Xs[(w * 16 + l16) * 520 + ks * 32 + quad * 8];
            short8 q = *(const short8*)&Qs[l16 * 520 + ks * 32 + quad * 8];
            acc = __builtin_amdgcn_mfma_f32_16x16x32_bf16(a, q, acc, 0, 0, 0);
        }
        #pragma unroll
        for (int r = 0; r < 4; r++)
            Sc[l16 * 100 + w * 16 + quad * 4 + r] = acc[r] * 0.125f;
    }
    __syncthreads();

    if (w < 8) {
        float e0 = __expf(Sc[w * 100 + lane]);
        float e1 = (lane < 32) ? __expf(Sc[w * 100 + 64 + lane]) : 0.f;
        float l = wave_sum(e0 + e1);
        Ps[w * 104 + lane] = f2bf(e0);
        if (lane < 32) Ps[w * 104 + 64 + lane] = f2bf(e1);
        if (lane == 0) linv[w] = 1.0f / l;
    } else {
        Ps[w * 104 + lane] = 0;
        if (lane < 40) Ps[w * 104 + 64 + lane] = 0;
    }
    if (t < 96) {
        float v = sm_[t]; int r = 0;
        for (int j = 0; j < 96; j++) {
            float u = sm_[j];
            r += (u > v) || (u == v && j < t);
        }
        srt[r] = v;
    }
    __syncthreads();

    #pragma unroll
    for (int jj = 0; jj < 2; jj++) {
        int n0 = (w * 2 + jj) * 16;
        f32x4 acc;
        for (int e = 0; e < 4; e++) acc[e] = 0.f;
        #pragma unroll
        for (int ks = 0; ks < 3; ks++) {
            short8 ap = *(const short8*)&Ps[l16 * 104 + ks * 32 + quad * 8];
            short8 bx;
            #pragma unroll
            for (int j = 0; j < 8; j++)
                bx[j] = (short)Xs[(ks * 32 + quad * 8 + j) * 520 + n0 + l16];
            acc = __builtin_amdgcn_mfma_f32_16x16x32_bf16(ap, bx, acc, 0, 0, 0);
        }
        if (quad < 2) {
            #pragma unroll
            for (int r = 0; r < 4; r++) {
                int h = quad * 4 + r;
                u_allb[((size_t)b * 8 + h) * 512 + n0 + l16] = f2bf(acc[r] * linv[h]);
            }
        }
    }
    if (t < 3) {
        float mean = 0.f;
        #pragma unroll 8
        for (int i = 0; i < 32; i++) mean += srt[t * 32 + i];
        mean *= (1.0f / 32.0f);
        float var = 0.f;
        #pragma unroll 8
        for (int i = 0; i < 32; i++) { float d = srt[t * 32 + i] - mean; var += d * d; }
        var *= (1.0f / 31.0f);
        out_cs[b * 3 + t] = mean / (sqrtf(var) + 1e-6f);
    }
}

// ---------- K4: ghead: ctx_h = u_h @ Wv_h^T + bv_h (single-phase K=512), bf16 out ----------
__global__ __launch_bounds__(256) void ghead(const u16* __restrict__ u_allb,
                                             const u16* __restrict__ wvb,
                                             const float* __restrict__ bv,
                                             u16* __restrict__ ctxb)
{
    __shared__ __align__(16) u16 As[64 * 520];
    __shared__ __align__(16) u16 Bs[64 * 520];
    const int bid = blockIdx.x;
    const int m0 = (bid & 7) * 64, h = bid >> 3;
    const int t = threadIdx.x, lane = t & 63, w = t >> 6;
    const int wm = (w >> 1) * 32, wn = (w & 1) * 32;
    const int l16 = lane & 15, quad = lane >> 4;

    f32x4 acc[2][2];
    for (int i = 0; i < 2; i++)
        for (int j = 0; j < 2; j++)
            for (int e = 0; e < 4; e++) acc[i][j][e] = 0.f;

    stage64x512(u_allb + (size_t)m0 * 4096 + (size_t)h * 512, 4096, As);
    stage64x512(wvb + (size_t)h * 64 * 512, 512, Bs);
    __syncthreads();
    mfma_k512(As, Bs, acc);

    for (int i = 0; i < 2; i++) {
        int row = m0 + wm + i * 16 + quad * 4;
        for (int j = 0; j < 2; j++) {
            int col = wn + j * 16 + l16;
            float bb = bv[h * 64 + col];
            for (int r = 0; r < 4; r++)
                ctxb[(size_t)(row + r) * 512 + h * 64 + col] = f2bf(acc[i][j][r] + bb);
        }
    }
}

// ---------- K5: tail2 (128 blocks, both halves need only ctxb) ----------
// [0,64):   gcorr: corrected = ctx @ Wo^T + bo (fp32 out + row sumsq)
// [64,128): nsG:   ns[:,0:512] = G @ ctx^T + vb
__global__ __launch_bounds__(256) void tail2(const u16* __restrict__ ctxb,
                                             const u16* __restrict__ wob,
                                             const float* __restrict__ bias,
                                             float* __restrict__ Cf,
                                             float* __restrict__ corrSS,
                                             const u16* __restrict__ G,
                                             const float* __restrict__ vb,
                                             float* __restrict__ ns)
{
    __shared__ __align__(16) u16 As[64 * 520];
    __shared__ __align__(16) u16 Bs[64 * 520];
    const int bid = blockIdx.x;
    const int t = threadIdx.x, lane = t & 63, w = t >> 6;
    const int wm = (w >> 1) * 32, wn = (w & 1) * 32;
    const int l16 = lane & 15, quad = lane >> 4;

    f32x4 acc[2][2];
    for (int i = 0; i < 2; i++)
        for (int j = 0; j < 2; j++)
            for (int e = 0; e < 4; e++) acc[i][j][e] = 0.f;

    if (bid < 64) {
        // ---- gcorr ----
        const int m0 = (bid & 7) * 64, n0 = (bid >> 3) * 64;
        stage64x512(ctxb + (size_t)m0 * 512, 512, As);
        stage64x512(wob + (size_t)n0 * 512, 512, Bs);
        __syncthreads();
        mfma_k512(As, Bs, acc);
        #pragma unroll
        for (int i = 0; i < 2; i++) {
            #pragma unroll
            for (int r = 0; r < 4; r++) {
                int row = m0 + wm + i * 16 + quad * 4 + r;
                float s = 0.f;
                #pragma unroll
                for (int j = 0; j < 2; j++) {
                    int col = n0 + wn + j * 16 + l16;
                    float v = acc[i][j][r] + bias[col];
                    Cf[(size_t)row * 512 + col] = v;
                    s += v * v;
                }
                s += __shfl_xor(s, 1, 64); s += __shfl_xor(s, 2, 64);
                s += __shfl_xor(s, 4, 64); s += __shfl_xor(s, 8, 64);
                if (l16 == 0) atomicAdd(&corrSS[row], s);
            }
        }
        return;
    }

    // ---- nsG: ns[m][n] = G[m] . ctx[n] + vb[m] ----
    const int idx = bid - 64;
    const int m0 = (idx & 7) * 64, n0 = (idx >> 3) * 64;
    stage64x512(G + (size_t)m0 * 512, 512, As);
    stage64x512(ctxb + (size_t)n0 * 512, 512, Bs);
    __syncthreads();
    mfma_k512(As, Bs, acc);
    for (int i = 0; i < 2; i++) {
        int row = m0 + wm + i * 16 + quad * 4;
        for (int j = 0; j < 2; j++) {
            int col = n0 + wn + j * 16 + l16;
            for (int r = 0; r < 4; r++)
                ns[(size_t)(row + r) * 1024 + col] = acc[i][j][r] + vb[row + r];
        }
    }
}

// ---------- K6: top-5 + loss; per-wave top-5 (no sync) then single merge ----------
__global__ __launch_bounds__(256) void topk_loss(const float* __restrict__ ns,
                                                 const float* __restrict__ corrSS,
                                                 const float* __restrict__ tau_p_log,
                                                 const float* __restrict__ tau_n_log,
                                                 float* __restrict__ out_loss)
{
    __shared__ float invn[512];
    __shared__ float cv[20];
    __shared__ int   cjx[20];
    int b = blockIdx.x, t = threadIdx.x;
    int w = t >> 6, lane = t & 63;

    {
        float s0 = corrSS[t], s1 = corrSS[t + 256];
        invn[t]       = 1.0f / fmaxf(sqrtf(s0), EPS);
        invn[t + 256] = 1.0f / fmaxf(sqrtf(s1), EPS);
    }
    __syncthreads();

    const float4 raw = *(const float4*)(ns + (size_t)b * 1024 + t * 4);
    float lv[4] = {raw.x, raw.y, raw.z, raw.w};
    int   li[4] = {t * 4, t * 4 + 1, t * 4 + 2, t * 4 + 3};
    if (t < 128) {
        lv[0] *= invn[t * 4];     lv[1] *= invn[t * 4 + 1];
        lv[2] *= invn[t * 4 + 2]; lv[3] *= invn[t * 4 + 3];
    }
    #pragma unroll
    for (int i = 1; i < 4; i++) {
        float kv = lv[i]; int kx = li[i];
        int j = i - 1;
        #pragma unroll
        for (int k = 0; k < 3; k++) {
            if (j >= 0 && lv[j] < kv) { lv[j + 1] = lv[j]; li[j + 1] = li[j]; j--; }
        }
        lv[j + 1] = kv; li[j + 1] = kx;
    }
    int lp = 0;
    #pragma unroll
    for (int rd = 0; rd < 5; rd++) {
        float mv = (lp < 4) ? lv[lp] : -1e30f;
        int   mi = (lp < 4) ? li[lp] : 0;
        int   ml = lane;
        #pragma unroll
        for (int off = 32; off; off >>= 1) {
            float ov = __shfl_xor(mv, off, 64);
            int   oi = __shfl_xor(mi, off, 64);
            int   ol = __shfl_xor(ml, off, 64);
            if (ov > mv || (ov == mv && ol < ml)) { mv = ov; mi = oi; ml = ol; }
        }
        if (lane == ml) lp++;
        if (lane == 0) { cv[w * 5 + rd] = mv; cjx[w * 5 + rd] = mi; }
    }
    __syncthreads();
    if (w == 0) {
        float v  = (lane < 20) ? cv[lane] : -1e30f;
        int   jx = (lane < 20) ? cjx[lane] : 0;
        float tn = expf(tau_n_log[0]);
        float itn = 1.0f / tn;
        float nsum = 0.f; int coll = 0;
        #pragma unroll
        for (int rd = 0; rd < 5; rd++) {
            float mv = v; int ml = lane; int mj = jx;
            #pragma unroll
            for (int off = 32; off; off >>= 1) {
                float ov = __shfl_xor(mv, off, 64);
                int   oj = __shfl_xor(mj, off, 64);
                int   ol = __shfl_xor(ml, off, 64);
                if (ov > mv || (ov == mv && ol < ml)) { mv = ov; mj = oj; ml = ol; }
            }
            int mult = (mj < 512) ? 2 : 1;
            int take = 5 - coll;
            take = (mult < take) ? mult : take;
            if (take < 0) take = 0;
            nsum += (float)take * __expf(mv * itn);
            coll += take;
            if (lane == ml) v = -1e30f;
        }
        if (lane == 0) {
            float pos = ns[(size_t)b * 1024 + b] * invn[b];   // cos(vis_n, corr_n)
            float tp = expf(tau_p_log[0]);
            float p = expf(pos / tp);
            float term = logf(p / (p + nsum + 1e-8f));
            atomicAdd(out_loss, -term * (1.0f / 512.0f));
        }
    }
}

// ---------- launch ----------
extern "C" void kernel_launch(void* const* d_in, const int* in_sizes, int n_in,
                              void* d_out, int out_size, void* d_ws, size_t ws_size,
                              hipStream_t stream) {
    const float* vis = (const float*)d_in[0];
    const float* tf  = (const float*)d_in[1];
    const float* ipw = (const float*)d_in[2];
    const float* ipb = (const float*)d_in[3];
    const float* opw = (const float*)d_in[4];
    const float* opb = (const float*)d_in[5];
    const float* tm  = (const float*)d_in[6];
    const float* tpl = (const float*)d_in[7];
    const float* tnl = (const float*)d_in[8];

    float* out       = (float*)d_out;
    float* out_loss  = out;
    float* out_corr  = out + 1;                  // (512,512)
    float* out_cs    = out + 1 + 512 * 512;      // (512,3)

    char* p = (char*)d_ws;
    auto alloc = [&](size_t bytes) { char* r = p; p += (bytes + 255) & ~(size_t)255; return r; };
    float* vis_n  = (float*)alloc(512 * 512 * 4);
    u16*   vis_nb = (u16*)  alloc(512 * 512 * 2);
    u16*   vis_b  = (u16*)  alloc(512 * 512 * 2);
    u16*   wqb    = (u16*)  alloc(512 * 512 * 2);
    u16*   wvb    = (u16*)  alloc(512 * 512 * 2);
    u16*   wob    = (u16*)  alloc(512 * 512 * 2);
    u16*   wkT    = (u16*)  alloc(512 * 512 * 2);
    u16*   woT    = (u16*)  alloc(512 * 512 * 2);
    u16*   G      = (u16*)  alloc(512 * 512 * 2);
    u16*   qkb    = (u16*)  alloc((size_t)512 * 8 * 512 * 2);
    u16*   u_allb = (u16*)  alloc((size_t)512 * 8 * 512 * 2);
    u16*   ctxb   = (u16*)  alloc(512 * 512 * 2);
    u16*   negsb  = (u16*)  alloc(1024 * 512 * 2);
    float* ns     = (float*)alloc(512 * 1024 * 4);
    float* corrSS = (float*)alloc(512 * 4);
    float* vb     = (float*)alloc(512 * 4);

    const float* bv = ipb + 2 * 512;

    prep<<<1152, 256, 0, stream>>>(vis, ipw, opw, tm, vis_n, vis_nb, vis_b,
                                   wqb, wvb, wob, negsb, wkT, woT, corrSS, out_loss);
    mid<<<200, 256, 0, stream>>>(vis_b, vis_nb, wqb, ipb, wkT, qkb, negsb, ns,
                                 woT, G, opb, vb, vis_n);
    attn<<<512, 1024, 0, stream>>>(tf, vis_n, qkb, u_allb, out_cs);
    ghead<<<64, 256, 0, stream>>>(u_allb, wvb, bv, ctxb);
    tail2<<<128, 256, 0, stream>>>(ctxb, wob, opb, out_corr, corrSS, G, vb, ns);
    topk_loss<<<512, 256, 0, stream>>>(ns, corrSS, tpl, tnl, out_loss);
}